// Round 9
// baseline (1778.501 us; speedup 1.0000x reference)
//
#include <hip/hip_runtime.h>
#include <hip/hip_bf16.h>
#include <math.h>

#define B_ 16
#define T_ 128
#define S_ 256
#define H_ 512
#define M_ 512
#define V_ 32000

typedef __attribute__((ext_vector_type(8))) short short8v;
typedef __attribute__((ext_vector_type(4))) float float4v;

// ---------------- embedding gather ----------------
__global__ __launch_bounds__(128) void k_gather(const int* __restrict__ tgt,
    const float* __restrict__ embed, float* __restrict__ x)
{
  const int row = blockIdx.x;          // b*T+t
  const int v = tgt[row];
  const float4* src = (const float4*)(embed + (size_t)v * H_);
  float4* dst = (float4*)(x + (size_t)row * H_);
  dst[threadIdx.x] = src[threadIdx.x];
}

// ---------------- f32 NT GEMM + bias (xg0 only) ----------------
__global__ __launch_bounds__(256) void k_gemm_nt_bias(const float* __restrict__ A,
    const float* __restrict__ Bm, const float* __restrict__ bias,
    float* __restrict__ C, int N)
{
  __shared__ float As[64][33];
  __shared__ float Bs[64][33];
  const int tid = threadIdx.x;
  const int tm = tid >> 4, tn = tid & 15;
  const float* Ab = A  + (size_t)blockIdx.y * 64 * 512;
  const float* Bb = Bm + (size_t)blockIdx.x * 64 * 512;
  float acc00=0.f,acc01=0.f,acc02=0.f,acc03=0.f;
  float acc10=0.f,acc11=0.f,acc12=0.f,acc13=0.f;
  float acc20=0.f,acc21=0.f,acc22=0.f,acc23=0.f;
  float acc30=0.f,acc31=0.f,acc32=0.f,acc33=0.f;
  for (int k0 = 0; k0 < 512; k0 += 32) {
#pragma unroll
    for (int i = 0; i < 8; ++i) {
      int v = tid + i * 256;
      int row = v >> 5, col = v & 31;
      As[row][col] = Ab[(size_t)row * 512 + k0 + col];
      Bs[row][col] = Bb[(size_t)row * 512 + k0 + col];
    }
    __syncthreads();
#pragma unroll
    for (int kk = 0; kk < 32; ++kk) {
      float a0 = As[tm*4+0][kk], a1 = As[tm*4+1][kk];
      float a2 = As[tm*4+2][kk], a3 = As[tm*4+3][kk];
      float b0 = Bs[tn*4+0][kk], b1 = Bs[tn*4+1][kk];
      float b2 = Bs[tn*4+2][kk], b3 = Bs[tn*4+3][kk];
      acc00 += a0*b0; acc01 += a0*b1; acc02 += a0*b2; acc03 += a0*b3;
      acc10 += a1*b0; acc11 += a1*b1; acc12 += a1*b2; acc13 += a1*b3;
      acc20 += a2*b0; acc21 += a2*b1; acc22 += a2*b2; acc23 += a2*b3;
      acc30 += a3*b0; acc31 += a3*b1; acc32 += a3*b2; acc33 += a3*b3;
    }
    __syncthreads();
  }
  const int mbase = blockIdx.y*64 + tm*4;
  const int nbase = blockIdx.x*64 + tn*4;
  float bj0 = bias[nbase+0], bj1 = bias[nbase+1], bj2 = bias[nbase+2], bj3 = bias[nbase+3];
  float* Cr0 = C + (size_t)(mbase+0)*N + nbase;
  float* Cr1 = C + (size_t)(mbase+1)*N + nbase;
  float* Cr2 = C + (size_t)(mbase+2)*N + nbase;
  float* Cr3 = C + (size_t)(mbase+3)*N + nbase;
  Cr0[0]=acc00+bj0; Cr0[1]=acc01+bj1; Cr0[2]=acc02+bj2; Cr0[3]=acc03+bj3;
  Cr1[0]=acc10+bj0; Cr1[1]=acc11+bj1; Cr1[2]=acc12+bj2; Cr1[3]=acc13+bj3;
  Cr2[0]=acc20+bj0; Cr2[1]=acc21+bj1; Cr2[2]=acc22+bj2; Cr2[3]=acc23+bj3;
  Cr3[0]=acc30+bj0; Cr3[1]=acc31+bj1; Cr3[2]=acc32+bj2; Cr3[3]=acc33+bj3;
}

// bulk coherent load: 8x dwordx4, LLC-visible (sc0 sc1), waitcnt inside asm.
__device__ inline void bulk8_to_lds(const float* rowbase, int sc, float* dstrow)
{
  const float* p = rowbase + sc * 4;
  float4 a, b, c, d, e, f, g, h;
  asm volatile(
    "global_load_dwordx4 %0, %[p], off sc0 sc1\n\t"
    "global_load_dwordx4 %1, %[p], off offset:256 sc0 sc1\n\t"
    "global_load_dwordx4 %2, %[p], off offset:512 sc0 sc1\n\t"
    "global_load_dwordx4 %3, %[p], off offset:768 sc0 sc1\n\t"
    "global_load_dwordx4 %4, %[p], off offset:1024 sc0 sc1\n\t"
    "global_load_dwordx4 %5, %[p], off offset:1280 sc0 sc1\n\t"
    "global_load_dwordx4 %6, %[p], off offset:1536 sc0 sc1\n\t"
    "global_load_dwordx4 %7, %[p], off offset:1792 sc0 sc1\n\t"
    "s_waitcnt vmcnt(0)"
    : "=&v"(a), "=&v"(b), "=&v"(c), "=&v"(d),
      "=&v"(e), "=&v"(f), "=&v"(g), "=&v"(h)
    : [p]"v"(p)
    : "memory");
  *(float4*)&dstrow[(0*16 + sc) * 4] = a;
  *(float4*)&dstrow[(1*16 + sc) * 4] = b;
  *(float4*)&dstrow[(2*16 + sc) * 4] = c;
  *(float4*)&dstrow[(3*16 + sc) * 4] = d;
  *(float4*)&dstrow[(4*16 + sc) * 4] = e;
  *(float4*)&dstrow[(5*16 + sc) * 4] = f;
  *(float4*)&dstrow[(6*16 + sc) * 4] = g;
  *(float4*)&dstrow[(7*16 + sc) * 4] = h;
}

__device__ inline float4 load16_coh(const float* p)
{
  float4 v;
  asm volatile(
    "global_load_dwordx4 %0, %1, off sc0 sc1\n\t"
    "s_waitcnt vmcnt(0)"
    : "=v"(v) : "v"(p) : "memory");
  return v;
}

// ---------------- fused 2-layer GRU + batch-owned attention workers ----------------
// Grid 256 x 256 thr. WGs [0,64): layer 0 (8 dims). WGs [64,192): layer 1 (4 dims).
// WGs [192,256): attention workers. Worker w owns batch b = w&15 and tt-block
// tg = w>>4 (tt in [tg*32, tg*32+32)): its enc[b] (512 KB) stays L2-resident
// across its 32 tasks. Polls fB[tt] flags (FMA-burn = heater), coherent-loads
// the y1 row, computes softmax+context, writes attn_out. Tail-burns until the
// final fB flag so late GRU steps keep boosted clocks.
__global__ __launch_bounds__(256) void k_gru2(
    const float* __restrict__ xg0,
    const float* __restrict__ Whh0, const float* __restrict__ bhh0,
    const float* __restrict__ Wih1, const float* __restrict__ bih1,
    const float* __restrict__ Whh1, const float* __restrict__ bhh1,
    const float* __restrict__ hidden, const float* __restrict__ enc,
    float* __restrict__ out0, float* __restrict__ y1, float* __restrict__ hn,
    float* __restrict__ aout,
    unsigned int* __restrict__ fA, unsigned int* __restrict__ fB)
{
  __shared__ float Wl[24][520];
  __shared__ float hx[2][16 * 520];
  __shared__ float ps[24][16][17];
  __shared__ float orow[520];
  __shared__ float wbuf[256];
  __shared__ float red[8];
  const int bid = blockIdx.x;
  const int lt = threadIdx.x;

  // ---------------- attention workers (batch-owned) ----------------
  if (bid >= 192) {
    const int w = bid - 192;
    const int b = w & 15;            // owned batch
    const int tg = w >> 4;           // tt block 0..3
    for (int tt = tg * 32; tt < tg * 32 + 32; ++tt) {
      // wait for all 128 L1 flags of step tt (burn FMAs while polling)
      if (lt < 128) {
        const unsigned int* fl = &fB[tt * 128 + lt];
        float a0 = 1.0f + lt, a1 = 2.0f + lt, a2 = 3.0f, a3 = 4.0f;
        while (__hip_atomic_load(fl, __ATOMIC_RELAXED, __HIP_MEMORY_SCOPE_AGENT) == 0u) {
#pragma unroll 8
          for (int i = 0; i < 128; ++i) {
            a0 = __builtin_fmaf(a0, 1.0001f, 0.9999f);
            a1 = __builtin_fmaf(a1, 1.0001f, 0.9999f);
            a2 = __builtin_fmaf(a2, 1.0001f, 0.9999f);
            a3 = __builtin_fmaf(a3, 1.0001f, 0.9999f);
          }
          asm volatile("" :: "v"(a0), "v"(a1), "v"(a2), "v"(a3));
          __builtin_amdgcn_s_sleep(4);
        }
      }
      __syncthreads();
      const size_t row = (size_t)(b * T_ + tt);
      if (lt < 128)
        *(float4*)&orow[lt * 4] = load16_coh(y1 + row * 512 + lt * 4);
      __syncthreads();
      // scores: thread = source position s
      const float* er = enc + (size_t)(b * S_ + lt) * 512;
      float acc = 0.f;
      for (int k = 0; k < 512; k += 4) {
        float4 e = *(const float4*)(er + k);
        acc += orow[k]*e.x + orow[k+1]*e.y + orow[k+2]*e.z + orow[k+3]*e.w;
      }
      float m = acc;
#pragma unroll
      for (int off = 32; off > 0; off >>= 1) m = fmaxf(m, __shfl_down(m, off));
      if ((lt & 63) == 0) red[lt >> 6] = m;
      __syncthreads();
      float mx = fmaxf(fmaxf(red[0], red[1]), fmaxf(red[2], red[3]));
      float e = expf(acc - mx);
      wbuf[lt] = e;
      float s = e;
#pragma unroll
      for (int off = 32; off > 0; off >>= 1) s += __shfl_down(s, off);
      if ((lt & 63) == 0) red[4 + (lt >> 6)] = s;
      __syncthreads();
      const float inv = 1.f / (red[4] + red[5] + red[6] + red[7]);
      const int kk = lt * 2;
      float c0 = 0.f, c1 = 0.f;
      for (int s2 = 0; s2 < S_; ++s2) {
        float ws = wbuf[s2];
        float2 ev = *(const float2*)(enc + (size_t)(b * S_ + s2) * 512 + kk);
        c0 += ws * ev.x; c1 += ws * ev.y;
      }
      aout[row * 512 + kk]     = orow[kk]     + c0 * inv;
      aout[row * 512 + kk + 1] = orow[kk + 1] + c1 * inv;
      __syncthreads();      // protect orow/wbuf before next tt
    }
    // tail-burn: keep clocks boosted until the GRU's final step completes
    {
      __shared__ int done;
      if (lt == 0) done = 0;
      __syncthreads();
      const unsigned int* flag = &fB[(T_ - 1) * 128 + w];
      float a0 = 1.0f + lt, a1 = 2.0f + lt;
      for (;;) {
        if (lt == 0 &&
            __hip_atomic_load(flag, __ATOMIC_RELAXED, __HIP_MEMORY_SCOPE_AGENT) != 0u)
          done = 1;
        __syncthreads();
        if (done) break;
#pragma unroll 16
        for (int i = 0; i < 256; ++i) {
          a0 = __builtin_fmaf(a0, 1.0001f, 0.9999f);
          a1 = __builtin_fmaf(a1, 1.0001f, 0.9999f);
        }
        asm volatile("" :: "v"(a0), "v"(a1));
        __syncthreads();
      }
    }
    return;
  }

  const bool isB = bid >= 64;
  const int wg = isB ? bid - 64 : bid;
  const int dbase = isB ? wg * 4 : wg * 8;

  for (int r = 0; r < 24; ++r) {
    const float* src;
    if (!isB) src = Whh0 + (size_t)((r >> 3) * 512 + dbase + (r & 7)) * 512;
    else if (r < 12) src = Whh1 + (size_t)((r >> 2) * 512 + dbase + (r & 3)) * 512;
    else { int rr = r - 12; src = Wih1 + (size_t)((rr >> 2) * 512 + dbase + (rr & 3)) * 512; }
    Wl[r][lt] = src[lt];
    Wl[r][lt + 256] = src[lt + 256];
  }

  const int kq = lt & 15;
  const int bq = (lt >> 4) & 3;
  const int rgrp = lt >> 6;
  const int sb = lt >> 4;
  const int sc = lt & 15;
  float* ybuf = isB ? y1 : out0;
  const float* h0g = hidden + (isB ? 8192 : 0);

  const int rb = isB ? (lt >> 2) : (lt >> 3);
  const int rdl = isB ? (lt & 3) : (lt & 7);
  const int rdg = dbase + rdl;
  const int nred = isB ? 64 : 128;
  float bhr = 0.f, bhz = 0.f, bhn = 0.f, bir = 0.f, biz = 0.f, bin_ = 0.f;
  if (lt < nred) {
    const float* bhh = isB ? bhh1 : bhh0;
    bhr = bhh[rdg]; bhz = bhh[512 + rdg]; bhn = bhh[1024 + rdg];
    if (isB) { bir = bih1[rdg]; biz = bih1[512 + rdg]; bin_ = bih1[1024 + rdg]; }
  }

  for (int t = 0; t < T_; ++t) {
    // ---- P: poll flags ----
    if (!isB) {
      if (t > 0 && lt < 64) {
        unsigned v;
        do {
          v = __hip_atomic_load(&fA[(t - 1) * 64 + lt], __ATOMIC_RELAXED, __HIP_MEMORY_SCOPE_AGENT);
          if (__all(v != 0u)) break;
          __builtin_amdgcn_s_sleep(1);
        } while (true);
      }
    } else {
      if (lt < 64) {
        unsigned v;
        do {
          v = __hip_atomic_load(&fA[t * 64 + lt], __ATOMIC_RELAXED, __HIP_MEMORY_SCOPE_AGENT);
          if (__all(v != 0u)) break;
          __builtin_amdgcn_s_sleep(1);
        } while (true);
      } else if (t > 0 && lt < 192) {
        unsigned v;
        do {
          v = __hip_atomic_load(&fB[(t - 1) * 128 + (lt - 64)], __ATOMIC_RELAXED, __HIP_MEMORY_SCOPE_AGENT);
          if (__all(v != 0u)) break;
          __builtin_amdgcn_s_sleep(1);
        } while (true);
      }
    }
    __syncthreads();                                   // B0

    // ---- S: bulk-stage h rows ----
    if (t == 0) {
#pragma unroll
      for (int j = 0; j < 8; ++j)
        *(float4*)&hx[0][sb * 520 + (j * 16 + sc) * 4] =
            *(const float4*)(h0g + sb * 512 + (j * 16 + sc) * 4);
    } else {
      bulk8_to_lds(ybuf + (size_t)(sb * T_ + t - 1) * 512, sc, &hx[0][sb * 520]);
    }
    if (isB)
      bulk8_to_lds(out0 + (size_t)(sb * T_ + t) * 512, sc, &hx[1][sb * 520]);
    __syncthreads();                                   // B1

    // ---- M: register-tiled matvec ----
    const float* inb = (isB && rgrp >= 2) ? &hx[1][0] : &hx[0][0];
    float acc[6][4];
#pragma unroll
    for (int jr = 0; jr < 6; ++jr)
#pragma unroll
      for (int jb = 0; jb < 4; ++jb) acc[jr][jb] = 0.f;
#pragma unroll
    for (int i = 0; i < 8; ++i) {
      const int kb = kq * 4 + i * 64;
      float4 hv0 = *(const float4*)(inb + (bq * 4 + 0) * 520 + kb);
      float4 hv1 = *(const float4*)(inb + (bq * 4 + 1) * 520 + kb);
      float4 hv2 = *(const float4*)(inb + (bq * 4 + 2) * 520 + kb);
      float4 hv3 = *(const float4*)(inb + (bq * 4 + 3) * 520 + kb);
#pragma unroll
      for (int jr = 0; jr < 6; ++jr) {
        float4 wv = *(const float4*)(&Wl[rgrp * 6 + jr][kb]);
        acc[jr][0] += wv.x*hv0.x + wv.y*hv0.y + wv.z*hv0.z + wv.w*hv0.w;
        acc[jr][1] += wv.x*hv1.x + wv.y*hv1.y + wv.z*hv1.z + wv.w*hv1.w;
        acc[jr][2] += wv.x*hv2.x + wv.y*hv2.y + wv.z*hv2.z + wv.w*hv2.w;
        acc[jr][3] += wv.x*hv3.x + wv.y*hv3.y + wv.z*hv3.z + wv.w*hv3.w;
      }
    }
#pragma unroll
    for (int jr = 0; jr < 6; ++jr)
#pragma unroll
      for (int jb = 0; jb < 4; ++jb)
        ps[rgrp * 6 + jr][bq * 4 + jb][kq] = acc[jr][jb];
    __syncthreads();                                   // B2

    // ---- R: reduce + activations + store ----
    if (lt < nred) {
      float ghr, ghz, ghn, ixr, ixz, ixn;
      if (!isB) {
        float s0 = 0.f, s1 = 0.f, s2 = 0.f;
#pragma unroll
        for (int q = 0; q < 16; ++q) {
          s0 += ps[rdl][rb][q];
          s1 += ps[8 + rdl][rb][q];
          s2 += ps[16 + rdl][rb][q];
        }
        ghr = s0 + bhr; ghz = s1 + bhz; ghn = s2 + bhn;
        const float* xrow = xg0 + (size_t)(rb * T_ + t) * 1536;
        ixr = xrow[rdg]; ixz = xrow[512 + rdg]; ixn = xrow[1024 + rdg];
      } else {
        float s0=0.f,s1=0.f,s2=0.f,s3=0.f,s4=0.f,s5=0.f;
#pragma unroll
        for (int q = 0; q < 16; ++q) {
          s0 += ps[rdl][rb][q];       s1 += ps[4 + rdl][rb][q];  s2 += ps[8 + rdl][rb][q];
          s3 += ps[12 + rdl][rb][q];  s4 += ps[16 + rdl][rb][q]; s5 += ps[20 + rdl][rb][q];
        }
        ghr = s0 + bhr; ghz = s1 + bhz; ghn = s2 + bhn;
        ixr = s3 + bir; ixz = s4 + biz; ixn = s5 + bin_;
      }
      float rr = 1.f / (1.f + expf(-(ixr + ghr)));
      float zz = 1.f / (1.f + expf(-(ixz + ghz)));
      float nn = tanhf(ixn + rr * ghn);
      float hp = hx[0][rb * 520 + rdg];
      float hnew = (1.f - zz) * nn + zz * hp;
      __hip_atomic_store(&ybuf[(size_t)(rb * T_ + t) * 512 + rdg], hnew,
                         __ATOMIC_RELAXED, __HIP_MEMORY_SCOPE_AGENT);
      if (t == T_ - 1) hn[(isB ? 8192 : 0) + rb * 512 + rdg] = hnew;
    }
    __syncthreads();                                   // B3: vmcnt(0) drain
    if (lt == 0) {
      if (isB)
        __hip_atomic_store(&fB[t * 128 + wg], 1u, __ATOMIC_RELAXED, __HIP_MEMORY_SCOPE_AGENT);
      else
        __hip_atomic_store(&fA[t * 64 + wg], 1u, __ATOMIC_RELAXED, __HIP_MEMORY_SCOPE_AGENT);
    }
  }
}

// ---------------- persistent-B bf16 MFMA logits GEMM ----------------
__global__ __launch_bounds__(256) void k_logits(const float* __restrict__ A,
    const float* __restrict__ Bm, const float* __restrict__ bias,
    float* __restrict__ C)
{
  __shared__ unsigned short Bs[128 * 512];   // swizzled: byte ^= (row&7)<<4
  __shared__ unsigned short As[128 * 64];
  const int tid = threadIdx.x;
  const int nbase = blockIdx.x * 128;
  const int wv = tid >> 6;
  const int l  = tid & 63;
  const int wr = wv >> 1, wc = wv & 1;
  const int r = l & 15, q = l >> 4;

  for (int i = 0; i < 32; ++i) {
    const int gid = tid + i * 256;
    const int row = gid >> 6, cg = gid & 63;
    const float* Bg = Bm + (size_t)(nbase + row) * 512 + cg * 8;
    float4 g0 = *(const float4*)(Bg);
    float4 g1 = *(const float4*)(Bg + 4);
    union { short8v v; __hip_bfloat162 h2[4]; } pb;
    pb.h2[0] = __float22bfloat162_rn({g0.x, g0.y});
    pb.h2[1] = __float22bfloat162_rn({g0.z, g0.w});
    pb.h2[2] = __float22bfloat162_rn({g1.x, g1.y});
    pb.h2[3] = __float22bfloat162_rn({g1.z, g1.w});
    const int byte = (row * 1024 + cg * 16) ^ ((row & 7) << 4);
    *(short8v*)&Bs[byte >> 1] = pb.v;
  }
  __syncthreads();

  for (int m = 0; m < 16; ++m) {
    const int mbase = m * 128;
    float4v acc[4][4];
#pragma unroll
    for (int mi = 0; mi < 4; ++mi)
#pragma unroll
      for (int ni = 0; ni < 4; ++ni)
        acc[mi][ni] = (float4v){0.f, 0.f, 0.f, 0.f};

    for (int kc = 0; kc < 8; ++kc) {
#pragma unroll
      for (int i = 0; i < 4; ++i) {
        const int gid = tid + i * 256;
        const int row = gid >> 3, cg = gid & 7;
        const float* Ag = A + (size_t)(mbase + row) * 512 + kc * 64 + cg * 8;
        float4 f0 = *(const float4*)(Ag);
        float4 f1 = *(const float4*)(Ag + 4);
        union { short8v v; __hip_bfloat162 h2[4]; } pa;
        pa.h2[0] = __float22bfloat162_rn({f0.x, f0.y});
        pa.h2[1] = __float22bfloat162_rn({f0.z, f0.w});
        pa.h2[2] = __float22bfloat162_rn({f1.x, f1.y});
        pa.h2[3] = __float22bfloat162_rn({f1.z, f1.w});
        const int byte = (row * 128 + cg * 16) ^ ((row & 7) << 4);
        *(short8v*)&As[byte >> 1] = pa.v;
      }
      __syncthreads();

#pragma unroll
      for (int k0s = 0; k0s < 2; ++k0s) {
        short8v af[4], bf[4];
#pragma unroll
        for (int mi = 0; mi < 4; ++mi) {
          const int row = wr * 64 + mi * 16 + r;
          const int byte = (row * 128 + k0s * 64 + q * 16) ^ ((row & 7) << 4);
          af[mi] = *(short8v*)&As[byte >> 1];
        }
#pragma unroll
        for (int ni = 0; ni < 4; ++ni) {
          const int row = wc * 64 + ni * 16 + r;
          const int byte = (row * 1024 + kc * 128 + k0s * 64 + q * 16) ^ ((row & 7) << 4);
          bf[ni] = *(short8v*)&Bs[byte >> 1];
        }
#pragma unroll
        for (int mi = 0; mi < 4; ++mi)
#pragma unroll
          for (int ni = 0; ni < 4; ++ni)
            acc[mi][ni] = __builtin_amdgcn_mfma_f32_16x16x32_bf16(af[mi], bf[ni], acc[mi][ni], 0, 0, 0);
      }
      __syncthreads();
    }

    const int mg = mbase + wr * 64;
    const int ng = nbase + wc * 64;
#pragma unroll
    for (int ni = 0; ni < 4; ++ni) {
      const int col = ng + ni * 16 + r;
      const float bj = bias[col];
#pragma unroll
      for (int mi = 0; mi < 4; ++mi) {
        const int rowb = mg + mi * 16 + q * 4;
        float4v v = acc[mi][ni];
        C[(size_t)(rowb + 0) * V_ + col] = v[0] + bj;
        C[(size_t)(rowb + 1) * V_ + col] = v[1] + bj;
        C[(size_t)(rowb + 2) * V_ + col] = v[2] + bj;
        C[(size_t)(rowb + 3) * V_ + col] = v[3] + bj;
      }
    }
  }
}

extern "C" void kernel_launch(void* const* d_in, const int* in_sizes, int n_in,
                              void* d_out, int out_size, void* d_ws, size_t ws_size,
                              hipStream_t stream)
{
  const int*   tgt    = (const int*)  d_in[0];
  const float* hidden = (const float*)d_in[1];
  const float* enc    = (const float*)d_in[2];
  const float* embed  = (const float*)d_in[3];
  const float* W_ih0  = (const float*)d_in[4];
  const float* W_hh0  = (const float*)d_in[5];
  const float* b_ih0  = (const float*)d_in[6];
  const float* b_hh0  = (const float*)d_in[7];
  const float* W_ih1  = (const float*)d_in[8];
  const float* W_hh1  = (const float*)d_in[9];
  const float* b_ih1  = (const float*)d_in[10];
  const float* b_hh1  = (const float*)d_in[11];
  const float* W_out  = (const float*)d_in[12];
  const float* b_out  = (const float*)d_in[13];
  float* out = (float*)d_out;

  float* ws   = (float*)d_ws;
  float* xbuf = ws;                          // 2048*512   (x, later attn_out)
  float* xg   = ws + 1048576;                // 2048*1536
  float* out0 = xg + 3145728;                // 2048*512
  float* y1   = out0 + 1048576;              // 2048*512
  unsigned int* fA = (unsigned int*)(y1 + 1048576);   // 128*64 flags
  unsigned int* fB = fA + T_ * 64;                    // 128*128 flags

  const size_t logitsN = (size_t)(B_*T_) * V_;
  float* hn = out + logitsN;
  float* cn = hn + 16384;

  hipMemsetAsync(fA, 0, (size_t)(T_ * 64 + T_ * 128) * sizeof(unsigned int), stream);
  hipMemsetAsync(cn, 0, (size_t)16384 * sizeof(float), stream);

  k_gather<<<dim3(B_*T_), dim3(128), 0, stream>>>(tgt, embed, xbuf);
  k_gemm_nt_bias<<<dim3(1536/64, (B_*T_)/64), dim3(256), 0, stream>>>(xbuf, W_ih0, b_ih0, xg, 1536);
  k_gru2<<<dim3(256), dim3(256), 0, stream>>>(xg, W_hh0, b_hh0, W_ih1, b_ih1,
                                              W_hh1, b_hh1, hidden, enc,
                                              out0, y1, hn, xbuf, fA, fB);
  k_logits<<<dim3(V_/128), dim3(256), 0, stream>>>(xbuf, W_out, b_out, out);
}

// Round 10
// 1402.973 us; speedup vs baseline: 1.2677x; 1.2677x over previous
//
#include <hip/hip_runtime.h>
#include <hip/hip_bf16.h>
#include <math.h>

#define B_ 16
#define T_ 128
#define S_ 256
#define H_ 512
#define M_ 512
#define V_ 32000

typedef __attribute__((ext_vector_type(8))) short short8v;
typedef __attribute__((ext_vector_type(4))) float float4v;

// ---------------- embedding gather ----------------
__global__ __launch_bounds__(128) void k_gather(const int* __restrict__ tgt,
    const float* __restrict__ embed, float* __restrict__ x)
{
  const int row = blockIdx.x;          // b*T+t
  const int v = tgt[row];
  const float4* src = (const float4*)(embed + (size_t)v * H_);
  float4* dst = (float4*)(x + (size_t)row * H_);
  dst[threadIdx.x] = src[threadIdx.x];
}

// ---------------- f32 NT GEMM + bias (xg0 only) ----------------
__global__ __launch_bounds__(256) void k_gemm_nt_bias(const float* __restrict__ A,
    const float* __restrict__ Bm, const float* __restrict__ bias,
    float* __restrict__ C, int N)
{
  __shared__ float As[64][33];
  __shared__ float Bs[64][33];
  const int tid = threadIdx.x;
  const int tm = tid >> 4, tn = tid & 15;
  const float* Ab = A  + (size_t)blockIdx.y * 64 * 512;
  const float* Bb = Bm + (size_t)blockIdx.x * 64 * 512;
  float acc00=0.f,acc01=0.f,acc02=0.f,acc03=0.f;
  float acc10=0.f,acc11=0.f,acc12=0.f,acc13=0.f;
  float acc20=0.f,acc21=0.f,acc22=0.f,acc23=0.f;
  float acc30=0.f,acc31=0.f,acc32=0.f,acc33=0.f;
  for (int k0 = 0; k0 < 512; k0 += 32) {
#pragma unroll
    for (int i = 0; i < 8; ++i) {
      int v = tid + i * 256;
      int row = v >> 5, col = v & 31;
      As[row][col] = Ab[(size_t)row * 512 + k0 + col];
      Bs[row][col] = Bb[(size_t)row * 512 + k0 + col];
    }
    __syncthreads();
#pragma unroll
    for (int kk = 0; kk < 32; ++kk) {
      float a0 = As[tm*4+0][kk], a1 = As[tm*4+1][kk];
      float a2 = As[tm*4+2][kk], a3 = As[tm*4+3][kk];
      float b0 = Bs[tn*4+0][kk], b1 = Bs[tn*4+1][kk];
      float b2 = Bs[tn*4+2][kk], b3 = Bs[tn*4+3][kk];
      acc00 += a0*b0; acc01 += a0*b1; acc02 += a0*b2; acc03 += a0*b3;
      acc10 += a1*b0; acc11 += a1*b1; acc12 += a1*b2; acc13 += a1*b3;
      acc20 += a2*b0; acc21 += a2*b1; acc22 += a2*b2; acc23 += a2*b3;
      acc30 += a3*b0; acc31 += a3*b1; acc32 += a3*b2; acc33 += a3*b3;
    }
    __syncthreads();
  }
  const int mbase = blockIdx.y*64 + tm*4;
  const int nbase = blockIdx.x*64 + tn*4;
  float bj0 = bias[nbase+0], bj1 = bias[nbase+1], bj2 = bias[nbase+2], bj3 = bias[nbase+3];
  float* Cr0 = C + (size_t)(mbase+0)*N + nbase;
  float* Cr1 = C + (size_t)(mbase+1)*N + nbase;
  float* Cr2 = C + (size_t)(mbase+2)*N + nbase;
  float* Cr3 = C + (size_t)(mbase+3)*N + nbase;
  Cr0[0]=acc00+bj0; Cr0[1]=acc01+bj1; Cr0[2]=acc02+bj2; Cr0[3]=acc03+bj3;
  Cr1[0]=acc10+bj0; Cr1[1]=acc11+bj1; Cr1[2]=acc12+bj2; Cr1[3]=acc13+bj3;
  Cr2[0]=acc20+bj0; Cr2[1]=acc21+bj1; Cr2[2]=acc22+bj2; Cr2[3]=acc23+bj3;
  Cr3[0]=acc30+bj0; Cr3[1]=acc31+bj1; Cr3[2]=acc32+bj2; Cr3[3]=acc33+bj3;
}

// bulk coherent load: 8x dwordx4, LLC-visible (sc0 sc1), waitcnt inside asm.
__device__ inline void bulk8_to_lds(const float* rowbase, int sc, float* dstrow)
{
  const float* p = rowbase + sc * 4;
  float4 a, b, c, d, e, f, g, h;
  asm volatile(
    "global_load_dwordx4 %0, %[p], off sc0 sc1\n\t"
    "global_load_dwordx4 %1, %[p], off offset:256 sc0 sc1\n\t"
    "global_load_dwordx4 %2, %[p], off offset:512 sc0 sc1\n\t"
    "global_load_dwordx4 %3, %[p], off offset:768 sc0 sc1\n\t"
    "global_load_dwordx4 %4, %[p], off offset:1024 sc0 sc1\n\t"
    "global_load_dwordx4 %5, %[p], off offset:1280 sc0 sc1\n\t"
    "global_load_dwordx4 %6, %[p], off offset:1536 sc0 sc1\n\t"
    "global_load_dwordx4 %7, %[p], off offset:1792 sc0 sc1\n\t"
    "s_waitcnt vmcnt(0)"
    : "=&v"(a), "=&v"(b), "=&v"(c), "=&v"(d),
      "=&v"(e), "=&v"(f), "=&v"(g), "=&v"(h)
    : [p]"v"(p)
    : "memory");
  *(float4*)&dstrow[(0*16 + sc) * 4] = a;
  *(float4*)&dstrow[(1*16 + sc) * 4] = b;
  *(float4*)&dstrow[(2*16 + sc) * 4] = c;
  *(float4*)&dstrow[(3*16 + sc) * 4] = d;
  *(float4*)&dstrow[(4*16 + sc) * 4] = e;
  *(float4*)&dstrow[(5*16 + sc) * 4] = f;
  *(float4*)&dstrow[(6*16 + sc) * 4] = g;
  *(float4*)&dstrow[(7*16 + sc) * 4] = h;
}

// ---------------- fused 2-layer GRU: flag sync + bulk 16B transport ----------------
// r7 champion, byte-identical: WGs [0,64) layer 0 (8 dims), [64,192) layer 1
// (4 dims, Whh1+Wih1 in LDS), [192,256) quiet heaters (1-lane poll, FMA burn).
__global__ __launch_bounds__(256) void k_gru2(
    const float* __restrict__ xg0,
    const float* __restrict__ Whh0, const float* __restrict__ bhh0,
    const float* __restrict__ Wih1, const float* __restrict__ bih1,
    const float* __restrict__ Whh1, const float* __restrict__ bhh1,
    const float* __restrict__ hidden,
    float* __restrict__ out0, float* __restrict__ y1, float* __restrict__ hn,
    unsigned int* __restrict__ fA, unsigned int* __restrict__ fB)
{
  __shared__ float Wl[24][520];
  __shared__ float hx[2][16 * 520];
  __shared__ float ps[24][16][17];
  const int bid = blockIdx.x;
  const int lt = threadIdx.x;

  // ---------------- heaters (quiet: one lane polls one flag) ----------------
  if (bid >= 192) {
    __shared__ int done;
    if (lt == 0) done = 0;
    __syncthreads();
    const unsigned int* flag = &fB[(T_ - 1) * 128 + (bid - 192)];
    float a0 = 1.0f + lt, a1 = 2.0f + lt, a2 = 3.0f, a3 = 4.0f;
    const float mb = 1.0001f, cb = 0.9999f;
    for (;;) {
#pragma unroll 16
      for (int i = 0; i < 512; ++i) {
        a0 = __builtin_fmaf(a0, mb, cb); a1 = __builtin_fmaf(a1, mb, cb);
        a2 = __builtin_fmaf(a2, mb, cb); a3 = __builtin_fmaf(a3, mb, cb);
      }
      if (lt == 0 &&
          __hip_atomic_load(flag, __ATOMIC_RELAXED, __HIP_MEMORY_SCOPE_AGENT) != 0u)
        done = 1;
      __syncthreads();
      if (done) break;
    }
    asm volatile("" :: "v"(a0), "v"(a1), "v"(a2), "v"(a3));
    return;
  }

  const bool isB = bid >= 64;
  const int wg = isB ? bid - 64 : bid;
  const int dbase = isB ? wg * 4 : wg * 8;

  for (int r = 0; r < 24; ++r) {
    const float* src;
    if (!isB) src = Whh0 + (size_t)((r >> 3) * 512 + dbase + (r & 7)) * 512;
    else if (r < 12) src = Whh1 + (size_t)((r >> 2) * 512 + dbase + (r & 3)) * 512;
    else { int rr = r - 12; src = Wih1 + (size_t)((rr >> 2) * 512 + dbase + (rr & 3)) * 512; }
    Wl[r][lt] = src[lt];
    Wl[r][lt + 256] = src[lt + 256];
  }

  const int kq = lt & 15;
  const int bq = (lt >> 4) & 3;
  const int rgrp = lt >> 6;
  const int sb = lt >> 4;
  const int sc = lt & 15;
  float* ybuf = isB ? y1 : out0;
  const float* h0g = hidden + (isB ? 8192 : 0);

  const int rb = isB ? (lt >> 2) : (lt >> 3);
  const int rdl = isB ? (lt & 3) : (lt & 7);
  const int rdg = dbase + rdl;
  const int nred = isB ? 64 : 128;
  float bhr = 0.f, bhz = 0.f, bhn = 0.f, bir = 0.f, biz = 0.f, bin_ = 0.f;
  if (lt < nred) {
    const float* bhh = isB ? bhh1 : bhh0;
    bhr = bhh[rdg]; bhz = bhh[512 + rdg]; bhn = bhh[1024 + rdg];
    if (isB) { bir = bih1[rdg]; biz = bih1[512 + rdg]; bin_ = bih1[1024 + rdg]; }
  }

  for (int t = 0; t < T_; ++t) {
    // ---- P: poll flags ----
    if (!isB) {
      if (t > 0 && lt < 64) {
        unsigned v;
        do {
          v = __hip_atomic_load(&fA[(t - 1) * 64 + lt], __ATOMIC_RELAXED, __HIP_MEMORY_SCOPE_AGENT);
          if (__all(v != 0u)) break;
          __builtin_amdgcn_s_sleep(1);
        } while (true);
      }
    } else {
      if (lt < 64) {
        unsigned v;
        do {
          v = __hip_atomic_load(&fA[t * 64 + lt], __ATOMIC_RELAXED, __HIP_MEMORY_SCOPE_AGENT);
          if (__all(v != 0u)) break;
          __builtin_amdgcn_s_sleep(1);
        } while (true);
      } else if (t > 0 && lt < 192) {
        unsigned v;
        do {
          v = __hip_atomic_load(&fB[(t - 1) * 128 + (lt - 64)], __ATOMIC_RELAXED, __HIP_MEMORY_SCOPE_AGENT);
          if (__all(v != 0u)) break;
          __builtin_amdgcn_s_sleep(1);
        } while (true);
      }
    }
    __syncthreads();                                   // B0

    // ---- S: bulk-stage h rows ----
    if (t == 0) {
#pragma unroll
      for (int j = 0; j < 8; ++j)
        *(float4*)&hx[0][sb * 520 + (j * 16 + sc) * 4] =
            *(const float4*)(h0g + sb * 512 + (j * 16 + sc) * 4);
    } else {
      bulk8_to_lds(ybuf + (size_t)(sb * T_ + t - 1) * 512, sc, &hx[0][sb * 520]);
    }
    if (isB)
      bulk8_to_lds(out0 + (size_t)(sb * T_ + t) * 512, sc, &hx[1][sb * 520]);
    __syncthreads();                                   // B1

    // ---- M: register-tiled matvec ----
    const float* inb = (isB && rgrp >= 2) ? &hx[1][0] : &hx[0][0];
    float acc[6][4];
#pragma unroll
    for (int jr = 0; jr < 6; ++jr)
#pragma unroll
      for (int jb = 0; jb < 4; ++jb) acc[jr][jb] = 0.f;
#pragma unroll
    for (int i = 0; i < 8; ++i) {
      const int kb = kq * 4 + i * 64;
      float4 hv0 = *(const float4*)(inb + (bq * 4 + 0) * 520 + kb);
      float4 hv1 = *(const float4*)(inb + (bq * 4 + 1) * 520 + kb);
      float4 hv2 = *(const float4*)(inb + (bq * 4 + 2) * 520 + kb);
      float4 hv3 = *(const float4*)(inb + (bq * 4 + 3) * 520 + kb);
#pragma unroll
      for (int jr = 0; jr < 6; ++jr) {
        float4 wv = *(const float4*)(&Wl[rgrp * 6 + jr][kb]);
        acc[jr][0] += wv.x*hv0.x + wv.y*hv0.y + wv.z*hv0.z + wv.w*hv0.w;
        acc[jr][1] += wv.x*hv1.x + wv.y*hv1.y + wv.z*hv1.z + wv.w*hv1.w;
        acc[jr][2] += wv.x*hv2.x + wv.y*hv2.y + wv.z*hv2.z + wv.w*hv2.w;
        acc[jr][3] += wv.x*hv3.x + wv.y*hv3.y + wv.z*hv3.z + wv.w*hv3.w;
      }
    }
#pragma unroll
    for (int jr = 0; jr < 6; ++jr)
#pragma unroll
      for (int jb = 0; jb < 4; ++jb)
        ps[rgrp * 6 + jr][bq * 4 + jb][kq] = acc[jr][jb];
    __syncthreads();                                   // B2

    // ---- R: reduce + activations + store ----
    if (lt < nred) {
      float ghr, ghz, ghn, ixr, ixz, ixn;
      if (!isB) {
        float s0 = 0.f, s1 = 0.f, s2 = 0.f;
#pragma unroll
        for (int q = 0; q < 16; ++q) {
          s0 += ps[rdl][rb][q];
          s1 += ps[8 + rdl][rb][q];
          s2 += ps[16 + rdl][rb][q];
        }
        ghr = s0 + bhr; ghz = s1 + bhz; ghn = s2 + bhn;
        const float* xrow = xg0 + (size_t)(rb * T_ + t) * 1536;
        ixr = xrow[rdg]; ixz = xrow[512 + rdg]; ixn = xrow[1024 + rdg];
      } else {
        float s0=0.f,s1=0.f,s2=0.f,s3=0.f,s4=0.f,s5=0.f;
#pragma unroll
        for (int q = 0; q < 16; ++q) {
          s0 += ps[rdl][rb][q];       s1 += ps[4 + rdl][rb][q];  s2 += ps[8 + rdl][rb][q];
          s3 += ps[12 + rdl][rb][q];  s4 += ps[16 + rdl][rb][q]; s5 += ps[20 + rdl][rb][q];
        }
        ghr = s0 + bhr; ghz = s1 + bhz; ghn = s2 + bhn;
        ixr = s3 + bir; ixz = s4 + biz; ixn = s5 + bin_;
      }
      float rr = 1.f / (1.f + expf(-(ixr + ghr)));
      float zz = 1.f / (1.f + expf(-(ixz + ghz)));
      float nn = tanhf(ixn + rr * ghn);
      float hp = hx[0][rb * 520 + rdg];
      float hnew = (1.f - zz) * nn + zz * hp;
      __hip_atomic_store(&ybuf[(size_t)(rb * T_ + t) * 512 + rdg], hnew,
                         __ATOMIC_RELAXED, __HIP_MEMORY_SCOPE_AGENT);
      if (t == T_ - 1) hn[(isB ? 8192 : 0) + rb * 512 + rdg] = hnew;
    }
    __syncthreads();                                   // B3: vmcnt(0) drain
    if (lt == 0) {
      if (isB)
        __hip_atomic_store(&fB[t * 128 + wg], 1u, __ATOMIC_RELAXED, __HIP_MEMORY_SCOPE_AGENT);
      else
        __hip_atomic_store(&fA[t * 64 + wg], 1u, __ATOMIC_RELAXED, __HIP_MEMORY_SCOPE_AGENT);
    }
  }
}

// ---------------- attention: one WG per (b,t) row ----------------
__global__ __launch_bounds__(256) void k_attn(const float* __restrict__ y,
    const float* __restrict__ enc, float* __restrict__ aout)
{
  __shared__ float orow[512];
  __shared__ float wbuf[256];
  __shared__ float red[8];
  const int row = blockIdx.x;        // b*T+t
  const int b = row >> 7;
  const int lt = threadIdx.x;
  orow[lt]       = y[(size_t)row*512 + lt];
  orow[lt + 256] = y[(size_t)row*512 + lt + 256];
  __syncthreads();
  const float* er = enc + (size_t)(b*S_ + lt) * 512;
  float acc = 0.f;
  for (int k = 0; k < 512; k += 4) {
    float4 e = *(const float4*)(er + k);
    acc += orow[k]*e.x + orow[k+1]*e.y + orow[k+2]*e.z + orow[k+3]*e.w;
  }
  float m = acc;
#pragma unroll
  for (int off = 32; off > 0; off >>= 1) m = fmaxf(m, __shfl_down(m, off));
  if ((lt & 63) == 0) red[lt >> 6] = m;
  __syncthreads();
  float mx = fmaxf(fmaxf(red[0], red[1]), fmaxf(red[2], red[3]));
  float e = expf(acc - mx);
  wbuf[lt] = e;
  float s = e;
#pragma unroll
  for (int off = 32; off > 0; off >>= 1) s += __shfl_down(s, off);
  if ((lt & 63) == 0) red[4 + (lt >> 6)] = s;
  __syncthreads();
  const float inv = 1.f / (red[4] + red[5] + red[6] + red[7]);
  const int kk = lt * 2;
  float c0 = 0.f, c1 = 0.f;
  for (int s2 = 0; s2 < S_; ++s2) {
    float ws = wbuf[s2];
    float2 ev = *(const float2*)(enc + (size_t)(b*S_ + s2)*512 + kk);
    c0 += ws * ev.x; c1 += ws * ev.y;
  }
  aout[(size_t)row*512 + kk]     = orow[kk]     + c0 * inv;
  aout[(size_t)row*512 + kk + 1] = orow[kk + 1] + c1 * inv;
}

// ---------------- persistent-B bf16 MFMA logits GEMM ----------------
__global__ __launch_bounds__(256) void k_logits(const float* __restrict__ A,
    const float* __restrict__ Bm, const float* __restrict__ bias,
    float* __restrict__ C)
{
  __shared__ unsigned short Bs[128 * 512];   // swizzled: byte ^= (row&7)<<4
  __shared__ unsigned short As[128 * 64];
  const int tid = threadIdx.x;
  const int nbase = blockIdx.x * 128;
  const int wv = tid >> 6;
  const int l  = tid & 63;
  const int wr = wv >> 1, wc = wv & 1;
  const int r = l & 15, q = l >> 4;

  for (int i = 0; i < 32; ++i) {
    const int gid = tid + i * 256;
    const int row = gid >> 6, cg = gid & 63;
    const float* Bg = Bm + (size_t)(nbase + row) * 512 + cg * 8;
    float4 g0 = *(const float4*)(Bg);
    float4 g1 = *(const float4*)(Bg + 4);
    union { short8v v; __hip_bfloat162 h2[4]; } pb;
    pb.h2[0] = __float22bfloat162_rn({g0.x, g0.y});
    pb.h2[1] = __float22bfloat162_rn({g0.z, g0.w});
    pb.h2[2] = __float22bfloat162_rn({g1.x, g1.y});
    pb.h2[3] = __float22bfloat162_rn({g1.z, g1.w});
    const int byte = (row * 1024 + cg * 16) ^ ((row & 7) << 4);
    *(short8v*)&Bs[byte >> 1] = pb.v;
  }
  __syncthreads();

  for (int m = 0; m < 16; ++m) {
    const int mbase = m * 128;
    float4v acc[4][4];
#pragma unroll
    for (int mi = 0; mi < 4; ++mi)
#pragma unroll
      for (int ni = 0; ni < 4; ++ni)
        acc[mi][ni] = (float4v){0.f, 0.f, 0.f, 0.f};

    for (int kc = 0; kc < 8; ++kc) {
#pragma unroll
      for (int i = 0; i < 4; ++i) {
        const int gid = tid + i * 256;
        const int row = gid >> 3, cg = gid & 7;
        const float* Ag = A + (size_t)(mbase + row) * 512 + kc * 64 + cg * 8;
        float4 f0 = *(const float4*)(Ag);
        float4 f1 = *(const float4*)(Ag + 4);
        union { short8v v; __hip_bfloat162 h2[4]; } pa;
        pa.h2[0] = __float22bfloat162_rn({f0.x, f0.y});
        pa.h2[1] = __float22bfloat162_rn({f0.z, f0.w});
        pa.h2[2] = __float22bfloat162_rn({f1.x, f1.y});
        pa.h2[3] = __float22bfloat162_rn({f1.z, f1.w});
        const int byte = (row * 128 + cg * 16) ^ ((row & 7) << 4);
        *(short8v*)&As[byte >> 1] = pa.v;
      }
      __syncthreads();

#pragma unroll
      for (int k0s = 0; k0s < 2; ++k0s) {
        short8v af[4], bf[4];
#pragma unroll
        for (int mi = 0; mi < 4; ++mi) {
          const int row = wr * 64 + mi * 16 + r;
          const int byte = (row * 128 + k0s * 64 + q * 16) ^ ((row & 7) << 4);
          af[mi] = *(short8v*)&As[byte >> 1];
        }
#pragma unroll
        for (int ni = 0; ni < 4; ++ni) {
          const int row = wc * 64 + ni * 16 + r;
          const int byte = (row * 1024 + kc * 128 + k0s * 64 + q * 16) ^ ((row & 7) << 4);
          bf[ni] = *(short8v*)&Bs[byte >> 1];
        }
#pragma unroll
        for (int mi = 0; mi < 4; ++mi)
#pragma unroll
          for (int ni = 0; ni < 4; ++ni)
            acc[mi][ni] = __builtin_amdgcn_mfma_f32_16x16x32_bf16(af[mi], bf[ni], acc[mi][ni], 0, 0, 0);
      }
      __syncthreads();
    }

    const int mg = mbase + wr * 64;
    const int ng = nbase + wc * 64;
#pragma unroll
    for (int ni = 0; ni < 4; ++ni) {
      const int col = ng + ni * 16 + r;
      const float bj = bias[col];
#pragma unroll
      for (int mi = 0; mi < 4; ++mi) {
        const int rowb = mg + mi * 16 + q * 4;
        float4v v = acc[mi][ni];
        C[(size_t)(rowb + 0) * V_ + col] = v[0] + bj;
        C[(size_t)(rowb + 1) * V_ + col] = v[1] + bj;
        C[(size_t)(rowb + 2) * V_ + col] = v[2] + bj;
        C[(size_t)(rowb + 3) * V_ + col] = v[3] + bj;
      }
    }
  }
}

extern "C" void kernel_launch(void* const* d_in, const int* in_sizes, int n_in,
                              void* d_out, int out_size, void* d_ws, size_t ws_size,
                              hipStream_t stream)
{
  const int*   tgt    = (const int*)  d_in[0];
  const float* hidden = (const float*)d_in[1];
  const float* enc    = (const float*)d_in[2];
  const float* embed  = (const float*)d_in[3];
  const float* W_ih0  = (const float*)d_in[4];
  const float* W_hh0  = (const float*)d_in[5];
  const float* b_ih0  = (const float*)d_in[6];
  const float* b_hh0  = (const float*)d_in[7];
  const float* W_ih1  = (const float*)d_in[8];
  const float* W_hh1  = (const float*)d_in[9];
  const float* b_ih1  = (const float*)d_in[10];
  const float* b_hh1  = (const float*)d_in[11];
  const float* W_out  = (const float*)d_in[12];
  const float* b_out  = (const float*)d_in[13];
  float* out = (float*)d_out;

  float* ws   = (float*)d_ws;
  float* xbuf = ws;                          // 2048*512   (x, later attn_out)
  float* xg   = ws + 1048576;                // 2048*1536
  float* out0 = xg + 3145728;                // 2048*512
  float* y1   = out0 + 1048576;              // 2048*512
  unsigned int* fA = (unsigned int*)(y1 + 1048576);   // 128*64 flags
  unsigned int* fB = fA + T_ * 64;                    // 128*128 flags

  const size_t logitsN = (size_t)(B_*T_) * V_;
  float* hn = out + logitsN;
  float* cn = hn + 16384;

  hipMemsetAsync(fA, 0, (size_t)(T_ * 64 + T_ * 128) * sizeof(unsigned int), stream);
  hipMemsetAsync(cn, 0, (size_t)16384 * sizeof(float), stream);

  k_gather<<<dim3(B_*T_), dim3(128), 0, stream>>>(tgt, embed, xbuf);
  k_gemm_nt_bias<<<dim3(1536/64, (B_*T_)/64), dim3(256), 0, stream>>>(xbuf, W_ih0, b_ih0, xg, 1536);
  k_gru2<<<dim3(256), dim3(256), 0, stream>>>(xg, W_hh0, b_hh0, W_ih1, b_ih1,
                                              W_hh1, b_hh1, hidden, out0, y1, hn, fA, fB);
  k_attn<<<dim3(B_*T_), dim3(256), 0, stream>>>(y1, enc, xbuf);
  k_logits<<<dim3(V_/128), dim3(256), 0, stream>>>(xbuf, W_out, b_out, out);
}

// Round 11
// 1326.390 us; speedup vs baseline: 1.3409x; 1.0577x over previous
//
#include <hip/hip_runtime.h>
#include <hip/hip_bf16.h>
#include <math.h>

#define B_ 16
#define T_ 128
#define S_ 256
#define H_ 512
#define M_ 512
#define V_ 32000
#define SENT 0x7FC0DEADu

typedef __attribute__((ext_vector_type(8))) short short8v;
typedef __attribute__((ext_vector_type(4))) float float4v;

// ---------------- sentinel fill ----------------
__global__ __launch_bounds__(512) void k_fill(unsigned int* __restrict__ p, int n)
{
  const int i = blockIdx.x * 512 + threadIdx.x;
  if (i < n) p[i] = SENT;
}

// ---------------- gather-fused bf16 MFMA GEMM for xg0 ----------------
// xg[2048][1536] = embed[tgt[row]] . W_ih0^T + b_ih0, f32 out.
__global__ __launch_bounds__(256) void k_xg_bf16(const int* __restrict__ tgt,
    const float* __restrict__ embed, const float* __restrict__ Bm,
    const float* __restrict__ bias, float* __restrict__ C)
{
  __shared__ unsigned short As[128 * 40];
  __shared__ unsigned short Bs[128 * 40];
  const int tid = threadIdx.x;
  const int nbase = blockIdx.x * 128;
  const int mbase = blockIdx.y * 128;
  const int wv = tid >> 6;
  const int l  = tid & 63;
  const int wr = wv >> 1, wc = wv & 1;
  const int r = l & 15, q = l >> 4;

  // gather indices for this thread's two staged rows (constant across k)
  const int row0 = tid >> 2, row1 = (tid + 256) >> 2;
  const int v0 = tgt[mbase + row0];
  const int v1 = tgt[mbase + row1];

  float4v acc[4][4];
#pragma unroll
  for (int mi = 0; mi < 4; ++mi)
#pragma unroll
    for (int ni = 0; ni < 4; ++ni)
      acc[mi][ni] = (float4v){0.f, 0.f, 0.f, 0.f};

  for (int k0 = 0; k0 < 512; k0 += 32) {
    __syncthreads();
#pragma unroll
    for (int h = 0; h < 2; ++h) {
      const int c = tid + h * 256;
      const int row = h ? row1 : row0;
      const int av  = h ? v1 : v0;
      const int cb = c & 3;
      const float* Ag = embed + (size_t)av * 512 + k0 + cb * 8;
      float4 f0 = *(const float4*)(Ag);
      float4 f1 = *(const float4*)(Ag + 4);
      union { short8v v; __hip_bfloat162 h2[4]; } pa;
      pa.h2[0] = __float22bfloat162_rn({f0.x, f0.y});
      pa.h2[1] = __float22bfloat162_rn({f0.z, f0.w});
      pa.h2[2] = __float22bfloat162_rn({f1.x, f1.y});
      pa.h2[3] = __float22bfloat162_rn({f1.z, f1.w});
      *(short8v*)&As[row * 40 + cb * 8] = pa.v;
      const float* Bg = Bm + (size_t)(nbase + row) * 512 + k0 + cb * 8;
      float4 g0 = *(const float4*)(Bg);
      float4 g1 = *(const float4*)(Bg + 4);
      union { short8v v; __hip_bfloat162 h2[4]; } pb;
      pb.h2[0] = __float22bfloat162_rn({g0.x, g0.y});
      pb.h2[1] = __float22bfloat162_rn({g0.z, g0.w});
      pb.h2[2] = __float22bfloat162_rn({g1.x, g1.y});
      pb.h2[3] = __float22bfloat162_rn({g1.z, g1.w});
      *(short8v*)&Bs[row * 40 + cb * 8] = pb.v;
    }
    __syncthreads();

    short8v af[4], bf[4];
#pragma unroll
    for (int mi = 0; mi < 4; ++mi)
      af[mi] = *(short8v*)&As[(wr * 64 + mi * 16 + r) * 40 + q * 8];
#pragma unroll
    for (int ni = 0; ni < 4; ++ni)
      bf[ni] = *(short8v*)&Bs[(wc * 64 + ni * 16 + r) * 40 + q * 8];
#pragma unroll
    for (int mi = 0; mi < 4; ++mi)
#pragma unroll
      for (int ni = 0; ni < 4; ++ni)
        acc[mi][ni] = __builtin_amdgcn_mfma_f32_16x16x32_bf16(af[mi], bf[ni], acc[mi][ni], 0, 0, 0);
  }

  const int mg = mbase + wr * 64;
  const int ng = nbase + wc * 64;
#pragma unroll
  for (int ni = 0; ni < 4; ++ni) {
    const int col = ng + ni * 16 + r;
    const float bj = bias[col];
#pragma unroll
    for (int mi = 0; mi < 4; ++mi) {
      const int rowb = mg + mi * 16 + q * 4;
      float4v v = acc[mi][ni];
      C[(size_t)(rowb + 0) * 1536 + col] = v[0] + bj;
      C[(size_t)(rowb + 1) * 1536 + col] = v[1] + bj;
      C[(size_t)(rowb + 2) * 1536 + col] = v[2] + bj;
      C[(size_t)(rowb + 3) * 1536 + col] = v[3] + bj;
    }
  }
}

// bulk coherent load: 8x dwordx4, LLC-visible (sc0 sc1), single waitcnt.
struct F4x8 { float4 a, b, c, d, e, f, g, h; };
__device__ inline F4x8 bulk8_ld(const float* rowbase, int sc)
{
  F4x8 r;
  const float* p = rowbase + sc * 4;
  asm volatile(
    "global_load_dwordx4 %0, %[p], off sc0 sc1\n\t"
    "global_load_dwordx4 %1, %[p], off offset:256 sc0 sc1\n\t"
    "global_load_dwordx4 %2, %[p], off offset:512 sc0 sc1\n\t"
    "global_load_dwordx4 %3, %[p], off offset:768 sc0 sc1\n\t"
    "global_load_dwordx4 %4, %[p], off offset:1024 sc0 sc1\n\t"
    "global_load_dwordx4 %5, %[p], off offset:1280 sc0 sc1\n\t"
    "global_load_dwordx4 %6, %[p], off offset:1536 sc0 sc1\n\t"
    "global_load_dwordx4 %7, %[p], off offset:1792 sc0 sc1\n\t"
    "s_waitcnt vmcnt(0)"
    : "=&v"(r.a), "=&v"(r.b), "=&v"(r.c), "=&v"(r.d),
      "=&v"(r.e), "=&v"(r.f), "=&v"(r.g), "=&v"(r.h)
    : [p]"v"(p)
    : "memory");
  return r;
}

__device__ inline bool anysent(const F4x8& r)
{
  auto c1 = [](float4 v) {
    return (__float_as_uint(v.x) == SENT) | (__float_as_uint(v.y) == SENT) |
           (__float_as_uint(v.z) == SENT) | (__float_as_uint(v.w) == SENT);
  };
  return c1(r.a) | c1(r.b) | c1(r.c) | c1(r.d) |
         c1(r.e) | c1(r.f) | c1(r.g) | c1(r.h);
}

// stage one h-row slice with sentinel-retry (detection == transport)
__device__ inline void stage_sent(const float* rowbase, int sc, float* dstrow)
{
  F4x8 r = bulk8_ld(rowbase, sc);
  while (anysent(r)) {
    __builtin_amdgcn_s_sleep(1);
    r = bulk8_ld(rowbase, sc);
  }
  *(float4*)&dstrow[(0*16 + sc) * 4] = r.a;
  *(float4*)&dstrow[(1*16 + sc) * 4] = r.b;
  *(float4*)&dstrow[(2*16 + sc) * 4] = r.c;
  *(float4*)&dstrow[(3*16 + sc) * 4] = r.d;
  *(float4*)&dstrow[(4*16 + sc) * 4] = r.e;
  *(float4*)&dstrow[(5*16 + sc) * 4] = r.f;
  *(float4*)&dstrow[(6*16 + sc) * 4] = r.g;
  *(float4*)&dstrow[(7*16 + sc) * 4] = r.h;
}

// ---------------- fused 2-layer GRU: sentinel dataflow + bulk transport ----------------
// WGs [0,64): layer 0 (8 dims). [64,192): layer 1 (4 dims, Whh1+Wih1 in LDS).
// [192,256): quiet heaters (1-lane poll of y1's last element). No flags, no
// fences: producers store h (relaxed agent, write-through); consumers bulk-load
// with sentinel retry — detection delivers the data in the same transaction.
__global__ __launch_bounds__(256) void k_gru2(
    const float* __restrict__ xg0,
    const float* __restrict__ Whh0, const float* __restrict__ bhh0,
    const float* __restrict__ Wih1, const float* __restrict__ bih1,
    const float* __restrict__ Whh1, const float* __restrict__ bhh1,
    const float* __restrict__ hidden,
    float* __restrict__ out0, float* __restrict__ y1, float* __restrict__ hn)
{
  __shared__ float Wl[24][520];
  __shared__ float hx[2][16 * 520];
  __shared__ float ps[24][16][17];
  const int bid = blockIdx.x;
  const int lt = threadIdx.x;

  // ---------------- heaters (quiet: one lane polls y1's last element) ----------------
  if (bid >= 192) {
    __shared__ int done;
    if (lt == 0) done = 0;
    __syncthreads();
    const float* flag = y1 + (size_t)(15 * T_ + 127) * 512 + 511;
    float a0 = 1.0f + lt, a1 = 2.0f + lt, a2 = 3.0f, a3 = 4.0f;
    const float mb = 1.0001f, cb = 0.9999f;
    for (;;) {
#pragma unroll 16
      for (int i = 0; i < 512; ++i) {
        a0 = __builtin_fmaf(a0, mb, cb); a1 = __builtin_fmaf(a1, mb, cb);
        a2 = __builtin_fmaf(a2, mb, cb); a3 = __builtin_fmaf(a3, mb, cb);
      }
      if (lt == 0 &&
          __float_as_uint(__hip_atomic_load(flag, __ATOMIC_RELAXED,
                                            __HIP_MEMORY_SCOPE_AGENT)) != SENT)
        done = 1;
      __syncthreads();
      if (done) break;
    }
    asm volatile("" :: "v"(a0), "v"(a1), "v"(a2), "v"(a3));
    return;
  }

  const bool isB = bid >= 64;
  const int wg = isB ? bid - 64 : bid;
  const int dbase = isB ? wg * 4 : wg * 8;

  for (int r = 0; r < 24; ++r) {
    const float* src;
    if (!isB) src = Whh0 + (size_t)((r >> 3) * 512 + dbase + (r & 7)) * 512;
    else if (r < 12) src = Whh1 + (size_t)((r >> 2) * 512 + dbase + (r & 3)) * 512;
    else { int rr = r - 12; src = Wih1 + (size_t)((rr >> 2) * 512 + dbase + (rr & 3)) * 512; }
    Wl[r][lt] = src[lt];
    Wl[r][lt + 256] = src[lt + 256];
  }

  const int kq = lt & 15;
  const int bq = (lt >> 4) & 3;
  const int rgrp = lt >> 6;
  const int sb = lt >> 4;
  const int sc = lt & 15;
  float* ybuf = isB ? y1 : out0;
  const float* h0g = hidden + (isB ? 8192 : 0);

  const int rb = isB ? (lt >> 2) : (lt >> 3);
  const int rdl = isB ? (lt & 3) : (lt & 7);
  const int rdg = dbase + rdl;
  const int nred = isB ? 64 : 128;
  float bhr = 0.f, bhz = 0.f, bhn = 0.f, bir = 0.f, biz = 0.f, bin_ = 0.f;
  if (lt < nred) {
    const float* bhh = isB ? bhh1 : bhh0;
    bhr = bhh[rdg]; bhz = bhh[512 + rdg]; bhn = bhh[1024 + rdg];
    if (isB) { bir = bih1[rdg]; biz = bih1[512 + rdg]; bin_ = bih1[1024 + rdg]; }
  }
  __syncthreads();

  for (int t = 0; t < T_; ++t) {
    // ---- S: stage h rows with sentinel-retry bulk loads ----
    if (t == 0) {
#pragma unroll
      for (int j = 0; j < 8; ++j)
        *(float4*)&hx[0][sb * 520 + (j * 16 + sc) * 4] =
            *(const float4*)(h0g + sb * 512 + (j * 16 + sc) * 4);
    } else {
      stage_sent(ybuf + (size_t)(sb * T_ + t - 1) * 512, sc, &hx[0][sb * 520]);
    }
    if (isB)
      stage_sent(out0 + (size_t)(sb * T_ + t) * 512, sc, &hx[1][sb * 520]);
    __syncthreads();                                   // B1

    // ---- M: register-tiled matvec ----
    const float* inb = (isB && rgrp >= 2) ? &hx[1][0] : &hx[0][0];
    float acc[6][4];
#pragma unroll
    for (int jr = 0; jr < 6; ++jr)
#pragma unroll
      for (int jb = 0; jb < 4; ++jb) acc[jr][jb] = 0.f;
#pragma unroll
    for (int i = 0; i < 8; ++i) {
      const int kb = kq * 4 + i * 64;
      float4 hv0 = *(const float4*)(inb + (bq * 4 + 0) * 520 + kb);
      float4 hv1 = *(const float4*)(inb + (bq * 4 + 1) * 520 + kb);
      float4 hv2 = *(const float4*)(inb + (bq * 4 + 2) * 520 + kb);
      float4 hv3 = *(const float4*)(inb + (bq * 4 + 3) * 520 + kb);
#pragma unroll
      for (int jr = 0; jr < 6; ++jr) {
        float4 wv = *(const float4*)(&Wl[rgrp * 6 + jr][kb]);
        acc[jr][0] += wv.x*hv0.x + wv.y*hv0.y + wv.z*hv0.z + wv.w*hv0.w;
        acc[jr][1] += wv.x*hv1.x + wv.y*hv1.y + wv.z*hv1.z + wv.w*hv1.w;
        acc[jr][2] += wv.x*hv2.x + wv.y*hv2.y + wv.z*hv2.z + wv.w*hv2.w;
        acc[jr][3] += wv.x*hv3.x + wv.y*hv3.y + wv.z*hv3.z + wv.w*hv3.w;
      }
    }
#pragma unroll
    for (int jr = 0; jr < 6; ++jr)
#pragma unroll
      for (int jb = 0; jb < 4; ++jb)
        ps[rgrp * 6 + jr][bq * 4 + jb][kq] = acc[jr][jb];
    __syncthreads();                                   // B2

    // ---- R: reduce + activations + store (relaxed agent; data IS the signal) ----
    if (lt < nred) {
      float ghr, ghz, ghn, ixr, ixz, ixn;
      if (!isB) {
        float s0 = 0.f, s1 = 0.f, s2 = 0.f;
#pragma unroll
        for (int q = 0; q < 16; ++q) {
          s0 += ps[rdl][rb][q];
          s1 += ps[8 + rdl][rb][q];
          s2 += ps[16 + rdl][rb][q];
        }
        ghr = s0 + bhr; ghz = s1 + bhz; ghn = s2 + bhn;
        const float* xrow = xg0 + (size_t)(rb * T_ + t) * 1536;
        ixr = xrow[rdg]; ixz = xrow[512 + rdg]; ixn = xrow[1024 + rdg];
      } else {
        float s0=0.f,s1=0.f,s2=0.f,s3=0.f,s4=0.f,s5=0.f;
#pragma unroll
        for (int q = 0; q < 16; ++q) {
          s0 += ps[rdl][rb][q];       s1 += ps[4 + rdl][rb][q];  s2 += ps[8 + rdl][rb][q];
          s3 += ps[12 + rdl][rb][q];  s4 += ps[16 + rdl][rb][q]; s5 += ps[20 + rdl][rb][q];
        }
        ghr = s0 + bhr; ghz = s1 + bhz; ghn = s2 + bhn;
        ixr = s3 + bir; ixz = s4 + biz; ixn = s5 + bin_;
      }
      float rr = 1.f / (1.f + expf(-(ixr + ghr)));
      float zz = 1.f / (1.f + expf(-(ixz + ghz)));
      float nn = tanhf(ixn + rr * ghn);
      float hp = hx[0][rb * 520 + rdg];
      float hnew = (1.f - zz) * nn + zz * hp;
      __hip_atomic_store(&ybuf[(size_t)(rb * T_ + t) * 512 + rdg], hnew,
                         __ATOMIC_RELAXED, __HIP_MEMORY_SCOPE_AGENT);
      if (t == T_ - 1) hn[(isB ? 8192 : 0) + rb * 512 + rdg] = hnew;
    }
    __syncthreads();                                   // B3: protect hx before next stage
  }
}

// ---------------- attention: one WG per (b,t) row ----------------
__global__ __launch_bounds__(256) void k_attn(const float* __restrict__ y,
    const float* __restrict__ enc, float* __restrict__ aout)
{
  __shared__ float orow[512];
  __shared__ float wbuf[256];
  __shared__ float red[8];
  const int row = blockIdx.x;        // b*T+t
  const int b = row >> 7;
  const int lt = threadIdx.x;
  orow[lt]       = y[(size_t)row*512 + lt];
  orow[lt + 256] = y[(size_t)row*512 + lt + 256];
  __syncthreads();
  const float* er = enc + (size_t)(b*S_ + lt) * 512;
  float acc = 0.f;
  for (int k = 0; k < 512; k += 4) {
    float4 e = *(const float4*)(er + k);
    acc += orow[k]*e.x + orow[k+1]*e.y + orow[k+2]*e.z + orow[k+3]*e.w;
  }
  float m = acc;
#pragma unroll
  for (int off = 32; off > 0; off >>= 1) m = fmaxf(m, __shfl_down(m, off));
  if ((lt & 63) == 0) red[lt >> 6] = m;
  __syncthreads();
  float mx = fmaxf(fmaxf(red[0], red[1]), fmaxf(red[2], red[3]));
  float e = expf(acc - mx);
  wbuf[lt] = e;
  float s = e;
#pragma unroll
  for (int off = 32; off > 0; off >>= 1) s += __shfl_down(s, off);
  if ((lt & 63) == 0) red[4 + (lt >> 6)] = s;
  __syncthreads();
  const float inv = 1.f / (red[4] + red[5] + red[6] + red[7]);
  const int kk = lt * 2;
  float c0 = 0.f, c1 = 0.f;
  for (int s2 = 0; s2 < S_; ++s2) {
    float ws = wbuf[s2];
    float2 ev = *(const float2*)(enc + (size_t)(b*S_ + s2)*512 + kk);
    c0 += ws * ev.x; c1 += ws * ev.y;
  }
  aout[(size_t)row*512 + kk]     = orow[kk]     + c0 * inv;
  aout[(size_t)row*512 + kk + 1] = orow[kk + 1] + c1 * inv;
}

// ---------------- persistent-B bf16 MFMA logits GEMM ----------------
__global__ __launch_bounds__(256) void k_logits(const float* __restrict__ A,
    const float* __restrict__ Bm, const float* __restrict__ bias,
    float* __restrict__ C)
{
  __shared__ unsigned short Bs[128 * 512];   // swizzled: byte ^= (row&7)<<4
  __shared__ unsigned short As[128 * 64];
  const int tid = threadIdx.x;
  const int nbase = blockIdx.x * 128;
  const int wv = tid >> 6;
  const int l  = tid & 63;
  const int wr = wv >> 1, wc = wv & 1;
  const int r = l & 15, q = l >> 4;

  for (int i = 0; i < 32; ++i) {
    const int gid = tid + i * 256;
    const int row = gid >> 6, cg = gid & 63;
    const float* Bg = Bm + (size_t)(nbase + row) * 512 + cg * 8;
    float4 g0 = *(const float4*)(Bg);
    float4 g1 = *(const float4*)(Bg + 4);
    union { short8v v; __hip_bfloat162 h2[4]; } pb;
    pb.h2[0] = __float22bfloat162_rn({g0.x, g0.y});
    pb.h2[1] = __float22bfloat162_rn({g0.z, g0.w});
    pb.h2[2] = __float22bfloat162_rn({g1.x, g1.y});
    pb.h2[3] = __float22bfloat162_rn({g1.z, g1.w});
    const int byte = (row * 1024 + cg * 16) ^ ((row & 7) << 4);
    *(short8v*)&Bs[byte >> 1] = pb.v;
  }
  __syncthreads();

  for (int m = 0; m < 16; ++m) {
    const int mbase = m * 128;
    float4v acc[4][4];
#pragma unroll
    for (int mi = 0; mi < 4; ++mi)
#pragma unroll
      for (int ni = 0; ni < 4; ++ni)
        acc[mi][ni] = (float4v){0.f, 0.f, 0.f, 0.f};

    for (int kc = 0; kc < 8; ++kc) {
#pragma unroll
      for (int i = 0; i < 4; ++i) {
        const int gid = tid + i * 256;
        const int row = gid >> 3, cg = gid & 7;
        const float* Ag = A + (size_t)(mbase + row) * 512 + kc * 64 + cg * 8;
        float4 f0 = *(const float4*)(Ag);
        float4 f1 = *(const float4*)(Ag + 4);
        union { short8v v; __hip_bfloat162 h2[4]; } pa;
        pa.h2[0] = __float22bfloat162_rn({f0.x, f0.y});
        pa.h2[1] = __float22bfloat162_rn({f0.z, f0.w});
        pa.h2[2] = __float22bfloat162_rn({f1.x, f1.y});
        pa.h2[3] = __float22bfloat162_rn({f1.z, f1.w});
        const int byte = (row * 128 + cg * 16) ^ ((row & 7) << 4);
        *(short8v*)&As[byte >> 1] = pa.v;
      }
      __syncthreads();

#pragma unroll
      for (int k0s = 0; k0s < 2; ++k0s) {
        short8v af[4], bf[4];
#pragma unroll
        for (int mi = 0; mi < 4; ++mi) {
          const int row = wr * 64 + mi * 16 + r;
          const int byte = (row * 128 + k0s * 64 + q * 16) ^ ((row & 7) << 4);
          af[mi] = *(short8v*)&As[byte >> 1];
        }
#pragma unroll
        for (int ni = 0; ni < 4; ++ni) {
          const int row = wc * 64 + ni * 16 + r;
          const int byte = (row * 1024 + kc * 128 + k0s * 64 + q * 16) ^ ((row & 7) << 4);
          bf[ni] = *(short8v*)&Bs[byte >> 1];
        }
#pragma unroll
        for (int mi = 0; mi < 4; ++mi)
#pragma unroll
          for (int ni = 0; ni < 4; ++ni)
            acc[mi][ni] = __builtin_amdgcn_mfma_f32_16x16x32_bf16(af[mi], bf[ni], acc[mi][ni], 0, 0, 0);
      }
      __syncthreads();
    }

    const int mg = mbase + wr * 64;
    const int ng = nbase + wc * 64;
#pragma unroll
    for (int ni = 0; ni < 4; ++ni) {
      const int col = ng + ni * 16 + r;
      const float bj = bias[col];
#pragma unroll
      for (int mi = 0; mi < 4; ++mi) {
        const int rowb = mg + mi * 16 + q * 4;
        float4v v = acc[mi][ni];
        C[(size_t)(rowb + 0) * V_ + col] = v[0] + bj;
        C[(size_t)(rowb + 1) * V_ + col] = v[1] + bj;
        C[(size_t)(rowb + 2) * V_ + col] = v[2] + bj;
        C[(size_t)(rowb + 3) * V_ + col] = v[3] + bj;
      }
    }
  }
}

extern "C" void kernel_launch(void* const* d_in, const int* in_sizes, int n_in,
                              void* d_out, int out_size, void* d_ws, size_t ws_size,
                              hipStream_t stream)
{
  const int*   tgt    = (const int*)  d_in[0];
  const float* hidden = (const float*)d_in[1];
  const float* enc    = (const float*)d_in[2];
  const float* embed  = (const float*)d_in[3];
  const float* W_ih0  = (const float*)d_in[4];
  const float* W_hh0  = (const float*)d_in[5];
  const float* b_ih0  = (const float*)d_in[6];
  const float* b_hh0  = (const float*)d_in[7];
  const float* W_ih1  = (const float*)d_in[8];
  const float* W_hh1  = (const float*)d_in[9];
  const float* b_ih1  = (const float*)d_in[10];
  const float* b_hh1  = (const float*)d_in[11];
  const float* W_out  = (const float*)d_in[12];
  const float* b_out  = (const float*)d_in[13];
  float* out = (float*)d_out;

  float* ws   = (float*)d_ws;
  float* xbuf = ws;                          // 2048*512  (attn_out)
  float* xg   = ws + 1048576;                // 2048*1536
  float* out0 = xg + 3145728;                // 2048*512
  float* y1   = out0 + 1048576;              // 2048*512 (contiguous after out0)

  const size_t logitsN = (size_t)(B_*T_) * V_;
  float* hn = out + logitsN;
  float* cn = hn + 16384;

  hipMemsetAsync(cn, 0, (size_t)16384 * sizeof(float), stream);

  k_fill<<<dim3(4096), dim3(512), 0, stream>>>((unsigned int*)out0, 2097152); // out0+y1
  k_xg_bf16<<<dim3(1536/128, 2048/128), dim3(256), 0, stream>>>(tgt, embed, W_ih0, b_ih0, xg);
  k_gru2<<<dim3(256), dim3(256), 0, stream>>>(xg, W_hh0, b_hh0, W_ih1, b_ih1,
                                              W_hh1, b_hh1, hidden, out0, y1, hn);
  k_attn<<<dim3(B_*T_), dim3(256), 0, stream>>>(y1, enc, xbuf);
  k_logits<<<dim3(V_/128), dim3(256), 0, stream>>>(xbuf, W_out, b_out, out);
}

// Round 12
// 1304.762 us; speedup vs baseline: 1.3631x; 1.0166x over previous
//
#include <hip/hip_runtime.h>
#include <hip/hip_bf16.h>
#include <math.h>

#define B_ 16
#define T_ 128
#define S_ 256
#define H_ 512
#define M_ 512
#define V_ 32000
#define SENT 0x7FC0DEADu

typedef __attribute__((ext_vector_type(8))) short short8v;
typedef __attribute__((ext_vector_type(4))) float float4v;

// ---------------- sentinel fill ----------------
__global__ __launch_bounds__(512) void k_fill(unsigned int* __restrict__ p, int n)
{
  const int i = blockIdx.x * 512 + threadIdx.x;
  if (i < n) p[i] = SENT;
}

// ---------------- gather-fused bf16 MFMA GEMM for xg0 ----------------
__global__ __launch_bounds__(256) void k_xg_bf16(const int* __restrict__ tgt,
    const float* __restrict__ embed, const float* __restrict__ Bm,
    const float* __restrict__ bias, float* __restrict__ C)
{
  __shared__ unsigned short As[128 * 40];
  __shared__ unsigned short Bs[128 * 40];
  const int tid = threadIdx.x;
  const int nbase = blockIdx.x * 128;
  const int mbase = blockIdx.y * 128;
  const int wv = tid >> 6;
  const int l  = tid & 63;
  const int wr = wv >> 1, wc = wv & 1;
  const int r = l & 15, q = l >> 4;

  const int row0 = tid >> 2, row1 = (tid + 256) >> 2;
  const int v0 = tgt[mbase + row0];
  const int v1 = tgt[mbase + row1];

  float4v acc[4][4];
#pragma unroll
  for (int mi = 0; mi < 4; ++mi)
#pragma unroll
    for (int ni = 0; ni < 4; ++ni)
      acc[mi][ni] = (float4v){0.f, 0.f, 0.f, 0.f};

  for (int k0 = 0; k0 < 512; k0 += 32) {
    __syncthreads();
#pragma unroll
    for (int h = 0; h < 2; ++h) {
      const int c = tid + h * 256;
      const int row = h ? row1 : row0;
      const int av  = h ? v1 : v0;
      const int cb = c & 3;
      const float* Ag = embed + (size_t)av * 512 + k0 + cb * 8;
      float4 f0 = *(const float4*)(Ag);
      float4 f1 = *(const float4*)(Ag + 4);
      union { short8v v; __hip_bfloat162 h2[4]; } pa;
      pa.h2[0] = __float22bfloat162_rn({f0.x, f0.y});
      pa.h2[1] = __float22bfloat162_rn({f0.z, f0.w});
      pa.h2[2] = __float22bfloat162_rn({f1.x, f1.y});
      pa.h2[3] = __float22bfloat162_rn({f1.z, f1.w});
      *(short8v*)&As[row * 40 + cb * 8] = pa.v;
      const float* Bg = Bm + (size_t)(nbase + row) * 512 + k0 + cb * 8;
      float4 g0 = *(const float4*)(Bg);
      float4 g1 = *(const float4*)(Bg + 4);
      union { short8v v; __hip_bfloat162 h2[4]; } pb;
      pb.h2[0] = __float22bfloat162_rn({g0.x, g0.y});
      pb.h2[1] = __float22bfloat162_rn({g0.z, g0.w});
      pb.h2[2] = __float22bfloat162_rn({g1.x, g1.y});
      pb.h2[3] = __float22bfloat162_rn({g1.z, g1.w});
      *(short8v*)&Bs[row * 40 + cb * 8] = pb.v;
    }
    __syncthreads();

    short8v af[4], bf[4];
#pragma unroll
    for (int mi = 0; mi < 4; ++mi)
      af[mi] = *(short8v*)&As[(wr * 64 + mi * 16 + r) * 40 + q * 8];
#pragma unroll
    for (int ni = 0; ni < 4; ++ni)
      bf[ni] = *(short8v*)&Bs[(wc * 64 + ni * 16 + r) * 40 + q * 8];
#pragma unroll
    for (int mi = 0; mi < 4; ++mi)
#pragma unroll
      for (int ni = 0; ni < 4; ++ni)
        acc[mi][ni] = __builtin_amdgcn_mfma_f32_16x16x32_bf16(af[mi], bf[ni], acc[mi][ni], 0, 0, 0);
  }

  const int mg = mbase + wr * 64;
  const int ng = nbase + wc * 64;
#pragma unroll
  for (int ni = 0; ni < 4; ++ni) {
    const int col = ng + ni * 16 + r;
    const float bj = bias[col];
#pragma unroll
    for (int mi = 0; mi < 4; ++mi) {
      const int rowb = mg + mi * 16 + q * 4;
      float4v v = acc[mi][ni];
      C[(size_t)(rowb + 0) * 1536 + col] = v[0] + bj;
      C[(size_t)(rowb + 1) * 1536 + col] = v[1] + bj;
      C[(size_t)(rowb + 2) * 1536 + col] = v[2] + bj;
      C[(size_t)(rowb + 3) * 1536 + col] = v[3] + bj;
    }
  }
}

// bulk coherent load: 8x dwordx4, LLC-visible (sc0 sc1), single waitcnt.
struct F4x8 { float4 a, b, c, d, e, f, g, h; };
__device__ inline F4x8 bulk8_ld(const float* rowbase, int sc)
{
  F4x8 r;
  const float* p = rowbase + sc * 4;
  asm volatile(
    "global_load_dwordx4 %0, %[p], off sc0 sc1\n\t"
    "global_load_dwordx4 %1, %[p], off offset:256 sc0 sc1\n\t"
    "global_load_dwordx4 %2, %[p], off offset:512 sc0 sc1\n\t"
    "global_load_dwordx4 %3, %[p], off offset:768 sc0 sc1\n\t"
    "global_load_dwordx4 %4, %[p], off offset:1024 sc0 sc1\n\t"
    "global_load_dwordx4 %5, %[p], off offset:1280 sc0 sc1\n\t"
    "global_load_dwordx4 %6, %[p], off offset:1536 sc0 sc1\n\t"
    "global_load_dwordx4 %7, %[p], off offset:1792 sc0 sc1\n\t"
    "s_waitcnt vmcnt(0)"
    : "=&v"(r.a), "=&v"(r.b), "=&v"(r.c), "=&v"(r.d),
      "=&v"(r.e), "=&v"(r.f), "=&v"(r.g), "=&v"(r.h)
    : [p]"v"(p)
    : "memory");
  return r;
}

// dual bulk load: 16 loads in flight, ONE waitcnt (merges L1's two stages)
__device__ inline void bulk16_ld(const float* r0base, const float* r1base, int sc,
                                 F4x8& x, F4x8& y)
{
  const float* p0 = r0base + sc * 4;
  const float* p1 = r1base + sc * 4;
  asm volatile(
    "global_load_dwordx4 %0, %[p0], off sc0 sc1\n\t"
    "global_load_dwordx4 %1, %[p0], off offset:256 sc0 sc1\n\t"
    "global_load_dwordx4 %2, %[p0], off offset:512 sc0 sc1\n\t"
    "global_load_dwordx4 %3, %[p0], off offset:768 sc0 sc1\n\t"
    "global_load_dwordx4 %4, %[p0], off offset:1024 sc0 sc1\n\t"
    "global_load_dwordx4 %5, %[p0], off offset:1280 sc0 sc1\n\t"
    "global_load_dwordx4 %6, %[p0], off offset:1536 sc0 sc1\n\t"
    "global_load_dwordx4 %7, %[p0], off offset:1792 sc0 sc1\n\t"
    "global_load_dwordx4 %8, %[p1], off sc0 sc1\n\t"
    "global_load_dwordx4 %9, %[p1], off offset:256 sc0 sc1\n\t"
    "global_load_dwordx4 %10, %[p1], off offset:512 sc0 sc1\n\t"
    "global_load_dwordx4 %11, %[p1], off offset:768 sc0 sc1\n\t"
    "global_load_dwordx4 %12, %[p1], off offset:1024 sc0 sc1\n\t"
    "global_load_dwordx4 %13, %[p1], off offset:1280 sc0 sc1\n\t"
    "global_load_dwordx4 %14, %[p1], off offset:1536 sc0 sc1\n\t"
    "global_load_dwordx4 %15, %[p1], off offset:1792 sc0 sc1\n\t"
    "s_waitcnt vmcnt(0)"
    : "=&v"(x.a), "=&v"(x.b), "=&v"(x.c), "=&v"(x.d),
      "=&v"(x.e), "=&v"(x.f), "=&v"(x.g), "=&v"(x.h),
      "=&v"(y.a), "=&v"(y.b), "=&v"(y.c), "=&v"(y.d),
      "=&v"(y.e), "=&v"(y.f), "=&v"(y.g), "=&v"(y.h)
    : [p0]"v"(p0), [p1]"v"(p1)
    : "memory");
}

__device__ inline bool anysent(const F4x8& r)
{
  auto c1 = [](float4 v) {
    return (__float_as_uint(v.x) == SENT) | (__float_as_uint(v.y) == SENT) |
           (__float_as_uint(v.z) == SENT) | (__float_as_uint(v.w) == SENT);
  };
  return c1(r.a) | c1(r.b) | c1(r.c) | c1(r.d) |
         c1(r.e) | c1(r.f) | c1(r.g) | c1(r.h);
}

__device__ inline void f4x8_store(const F4x8& r, int sc, float* dstrow)
{
  *(float4*)&dstrow[(0*16 + sc) * 4] = r.a;
  *(float4*)&dstrow[(1*16 + sc) * 4] = r.b;
  *(float4*)&dstrow[(2*16 + sc) * 4] = r.c;
  *(float4*)&dstrow[(3*16 + sc) * 4] = r.d;
  *(float4*)&dstrow[(4*16 + sc) * 4] = r.e;
  *(float4*)&dstrow[(5*16 + sc) * 4] = r.f;
  *(float4*)&dstrow[(6*16 + sc) * 4] = r.g;
  *(float4*)&dstrow[(7*16 + sc) * 4] = r.h;
}

// stage one row slice with sentinel-retry
__device__ inline void stage_sent(const float* rowbase, int sc, float* dstrow)
{
  F4x8 r = bulk8_ld(rowbase, sc);
  while (anysent(r)) {
    __builtin_amdgcn_s_sleep(1);
    r = bulk8_ld(rowbase, sc);
  }
  f4x8_store(r, sc, dstrow);
}

// stage two row slices: joint issue (1 waitcnt), independent retry
__device__ inline void stage2_sent(const float* r0base, const float* r1base,
                                   int sc, float* d0, float* d1)
{
  F4x8 x, y;
  bulk16_ld(r0base, r1base, sc, x, y);
  while (anysent(x)) {
    __builtin_amdgcn_s_sleep(1);
    x = bulk8_ld(r0base, sc);
  }
  f4x8_store(x, sc, d0);
  while (anysent(y)) {
    __builtin_amdgcn_s_sleep(1);
    y = bulk8_ld(r1base, sc);
  }
  f4x8_store(y, sc, d1);
}

// ---------------- fused 2-layer GRU: sentinel dataflow + bulk transport ----------------
__global__ __launch_bounds__(256) void k_gru2(
    const float* __restrict__ xg0,
    const float* __restrict__ Whh0, const float* __restrict__ bhh0,
    const float* __restrict__ Wih1, const float* __restrict__ bih1,
    const float* __restrict__ Whh1, const float* __restrict__ bhh1,
    const float* __restrict__ hidden,
    float* __restrict__ out0, float* __restrict__ y1, float* __restrict__ hn)
{
  __shared__ float Wl[24][520];
  __shared__ float hx[2][16 * 520];
  __shared__ float ps[24][16][17];
  const int bid = blockIdx.x;
  const int lt = threadIdx.x;

  // ---------------- heaters (quiet: one lane polls y1's last element) ----------------
  if (bid >= 192) {
    __shared__ int done;
    if (lt == 0) done = 0;
    __syncthreads();
    const float* flag = y1 + (size_t)(15 * T_ + 127) * 512 + 511;
    float a0 = 1.0f + lt, a1 = 2.0f + lt, a2 = 3.0f, a3 = 4.0f;
    const float mb = 1.0001f, cb = 0.9999f;
    for (;;) {
#pragma unroll 16
      for (int i = 0; i < 512; ++i) {
        a0 = __builtin_fmaf(a0, mb, cb); a1 = __builtin_fmaf(a1, mb, cb);
        a2 = __builtin_fmaf(a2, mb, cb); a3 = __builtin_fmaf(a3, mb, cb);
      }
      if (lt == 0 &&
          __float_as_uint(__hip_atomic_load(flag, __ATOMIC_RELAXED,
                                            __HIP_MEMORY_SCOPE_AGENT)) != SENT)
        done = 1;
      __syncthreads();
      if (done) break;
    }
    asm volatile("" :: "v"(a0), "v"(a1), "v"(a2), "v"(a3));
    return;
  }

  const bool isB = bid >= 64;
  const int wg = isB ? bid - 64 : bid;
  const int dbase = isB ? wg * 4 : wg * 8;

  for (int r = 0; r < 24; ++r) {
    const float* src;
    if (!isB) src = Whh0 + (size_t)((r >> 3) * 512 + dbase + (r & 7)) * 512;
    else if (r < 12) src = Whh1 + (size_t)((r >> 2) * 512 + dbase + (r & 3)) * 512;
    else { int rr = r - 12; src = Wih1 + (size_t)((rr >> 2) * 512 + dbase + (rr & 3)) * 512; }
    Wl[r][lt] = src[lt];
    Wl[r][lt + 256] = src[lt + 256];
  }

  const int kq = lt & 15;
  const int bq = (lt >> 4) & 3;
  const int rgrp = lt >> 6;
  const int sb = lt >> 4;
  const int sc = lt & 15;
  float* ybuf = isB ? y1 : out0;
  const float* h0g = hidden + (isB ? 8192 : 0);

  const int rb = isB ? (lt >> 2) : (lt >> 3);
  const int rdl = isB ? (lt & 3) : (lt & 7);
  const int rdg = dbase + rdl;
  const int nred = isB ? 64 : 128;
  float bhr = 0.f, bhz = 0.f, bhn = 0.f, bir = 0.f, biz = 0.f, bin_ = 0.f;
  if (lt < nred) {
    const float* bhh = isB ? bhh1 : bhh0;
    bhr = bhh[rdg]; bhz = bhh[512 + rdg]; bhn = bhh[1024 + rdg];
    if (isB) { bir = bih1[rdg]; biz = bih1[512 + rdg]; bin_ = bih1[1024 + rdg]; }
  }
  __syncthreads();

  for (int t = 0; t < T_; ++t) {
    // ---- xg prefetch (L0 reducers): issue early, consumed after B2 ----
    float pxr = 0.f, pxz = 0.f, pxn = 0.f;
    if (!isB && lt < 128) {
      const float* xrow = xg0 + (size_t)(rb * T_ + t) * 1536;
      pxr = xrow[rdg]; pxz = xrow[512 + rdg]; pxn = xrow[1024 + rdg];
    }

    // ---- S: stage h rows (sentinel-retry bulk loads) ----
    if (t == 0) {
#pragma unroll
      for (int j = 0; j < 8; ++j)
        *(float4*)&hx[0][sb * 520 + (j * 16 + sc) * 4] =
            *(const float4*)(h0g + sb * 512 + (j * 16 + sc) * 4);
      if (isB)
        stage_sent(out0 + (size_t)(sb * T_) * 512, sc, &hx[1][sb * 520]);
    } else if (!isB) {
      stage_sent(ybuf + (size_t)(sb * T_ + t - 1) * 512, sc, &hx[0][sb * 520]);
    } else {
      stage2_sent(ybuf + (size_t)(sb * T_ + t - 1) * 512,
                  out0 + (size_t)(sb * T_ + t) * 512,
                  sc, &hx[0][sb * 520], &hx[1][sb * 520]);
    }
    __syncthreads();                                   // B1

    // ---- M: register-tiled matvec ----
    const float* inb = (isB && rgrp >= 2) ? &hx[1][0] : &hx[0][0];
    float acc[6][4];
#pragma unroll
    for (int jr = 0; jr < 6; ++jr)
#pragma unroll
      for (int jb = 0; jb < 4; ++jb) acc[jr][jb] = 0.f;
#pragma unroll
    for (int i = 0; i < 8; ++i) {
      const int kb = kq * 4 + i * 64;
      float4 hv0 = *(const float4*)(inb + (bq * 4 + 0) * 520 + kb);
      float4 hv1 = *(const float4*)(inb + (bq * 4 + 1) * 520 + kb);
      float4 hv2 = *(const float4*)(inb + (bq * 4 + 2) * 520 + kb);
      float4 hv3 = *(const float4*)(inb + (bq * 4 + 3) * 520 + kb);
#pragma unroll
      for (int jr = 0; jr < 6; ++jr) {
        float4 wv = *(const float4*)(&Wl[rgrp * 6 + jr][kb]);
        acc[jr][0] += wv.x*hv0.x + wv.y*hv0.y + wv.z*hv0.z + wv.w*hv0.w;
        acc[jr][1] += wv.x*hv1.x + wv.y*hv1.y + wv.z*hv1.z + wv.w*hv1.w;
        acc[jr][2] += wv.x*hv2.x + wv.y*hv2.y + wv.z*hv2.z + wv.w*hv2.w;
        acc[jr][3] += wv.x*hv3.x + wv.y*hv3.y + wv.z*hv3.z + wv.w*hv3.w;
      }
    }
#pragma unroll
    for (int jr = 0; jr < 6; ++jr)
#pragma unroll
      for (int jb = 0; jb < 4; ++jb)
        ps[rgrp * 6 + jr][bq * 4 + jb][kq] = acc[jr][jb];
    __syncthreads();                                   // B2

    // ---- R: reduce + activations + store ----
    if (lt < nred) {
      float ghr, ghz, ghn, ixr, ixz, ixn;
      if (!isB) {
        float s0 = 0.f, s1 = 0.f, s2 = 0.f;
#pragma unroll
        for (int q = 0; q < 16; ++q) {
          s0 += ps[rdl][rb][q];
          s1 += ps[8 + rdl][rb][q];
          s2 += ps[16 + rdl][rb][q];
        }
        ghr = s0 + bhr; ghz = s1 + bhz; ghn = s2 + bhn;
        ixr = pxr; ixz = pxz; ixn = pxn;
      } else {
        float s0=0.f,s1=0.f,s2=0.f,s3=0.f,s4=0.f,s5=0.f;
#pragma unroll
        for (int q = 0; q < 16; ++q) {
          s0 += ps[rdl][rb][q];       s1 += ps[4 + rdl][rb][q];  s2 += ps[8 + rdl][rb][q];
          s3 += ps[12 + rdl][rb][q];  s4 += ps[16 + rdl][rb][q]; s5 += ps[20 + rdl][rb][q];
        }
        ghr = s0 + bhr; ghz = s1 + bhz; ghn = s2 + bhn;
        ixr = s3 + bir; ixz = s4 + biz; ixn = s5 + bin_;
      }
      float rr = 1.f / (1.f + expf(-(ixr + ghr)));
      float zz = 1.f / (1.f + expf(-(ixz + ghz)));
      float nn = tanhf(ixn + rr * ghn);
      float hp = hx[0][rb * 520 + rdg];
      float hnew = (1.f - zz) * nn + zz * hp;
      __hip_atomic_store(&ybuf[(size_t)(rb * T_ + t) * 512 + rdg], hnew,
                         __ATOMIC_RELAXED, __HIP_MEMORY_SCOPE_AGENT);
      if (t == T_ - 1) hn[(isB ? 8192 : 0) + rb * 512 + rdg] = hnew;
    }
    __syncthreads();                                   // B3: protect hx before next stage
  }
}

// ---------------- attention: one WG per (b,t) row ----------------
__global__ __launch_bounds__(256) void k_attn(const float* __restrict__ y,
    const float* __restrict__ enc, float* __restrict__ aout)
{
  __shared__ float orow[512];
  __shared__ float wbuf[256];
  __shared__ float red[8];
  const int row = blockIdx.x;        // b*T+t
  const int b = row >> 7;
  const int lt = threadIdx.x;
  orow[lt]       = y[(size_t)row*512 + lt];
  orow[lt + 256] = y[(size_t)row*512 + lt + 256];
  __syncthreads();
  const float* er = enc + (size_t)(b*S_ + lt) * 512;
  float acc = 0.f;
  for (int k = 0; k < 512; k += 4) {
    float4 e = *(const float4*)(er + k);
    acc += orow[k]*e.x + orow[k+1]*e.y + orow[k+2]*e.z + orow[k+3]*e.w;
  }
  float m = acc;
#pragma unroll
  for (int off = 32; off > 0; off >>= 1) m = fmaxf(m, __shfl_down(m, off));
  if ((lt & 63) == 0) red[lt >> 6] = m;
  __syncthreads();
  float mx = fmaxf(fmaxf(red[0], red[1]), fmaxf(red[2], red[3]));
  float e = expf(acc - mx);
  wbuf[lt] = e;
  float s = e;
#pragma unroll
  for (int off = 32; off > 0; off >>= 1) s += __shfl_down(s, off);
  if ((lt & 63) == 0) red[4 + (lt >> 6)] = s;
  __syncthreads();
  const float inv = 1.f / (red[4] + red[5] + red[6] + red[7]);
  const int kk = lt * 2;
  float c0 = 0.f, c1 = 0.f;
  for (int s2 = 0; s2 < S_; ++s2) {
    float ws = wbuf[s2];
    float2 ev = *(const float2*)(enc + (size_t)(b*S_ + s2)*512 + kk);
    c0 += ws * ev.x; c1 += ws * ev.y;
  }
  aout[(size_t)row*512 + kk]     = orow[kk]     + c0 * inv;
  aout[(size_t)row*512 + kk + 1] = orow[kk + 1] + c1 * inv;
}

// ---------------- persistent-B bf16 MFMA logits GEMM ----------------
__global__ __launch_bounds__(256) void k_logits(const float* __restrict__ A,
    const float* __restrict__ Bm, const float* __restrict__ bias,
    float* __restrict__ C)
{
  __shared__ unsigned short Bs[128 * 512];   // swizzled: byte ^= (row&7)<<4
  __shared__ unsigned short As[128 * 64];
  const int tid = threadIdx.x;
  const int nbase = blockIdx.x * 128;
  const int wv = tid >> 6;
  const int l  = tid & 63;
  const int wr = wv >> 1, wc = wv & 1;
  const int r = l & 15, q = l >> 4;

  for (int i = 0; i < 32; ++i) {
    const int gid = tid + i * 256;
    const int row = gid >> 6, cg = gid & 63;
    const float* Bg = Bm + (size_t)(nbase + row) * 512 + cg * 8;
    float4 g0 = *(const float4*)(Bg);
    float4 g1 = *(const float4*)(Bg + 4);
    union { short8v v; __hip_bfloat162 h2[4]; } pb;
    pb.h2[0] = __float22bfloat162_rn({g0.x, g0.y});
    pb.h2[1] = __float22bfloat162_rn({g0.z, g0.w});
    pb.h2[2] = __float22bfloat162_rn({g1.x, g1.y});
    pb.h2[3] = __float22bfloat162_rn({g1.z, g1.w});
    const int byte = (row * 1024 + cg * 16) ^ ((row & 7) << 4);
    *(short8v*)&Bs[byte >> 1] = pb.v;
  }
  __syncthreads();

  for (int m = 0; m < 16; ++m) {
    const int mbase = m * 128;
    float4v acc[4][4];
#pragma unroll
    for (int mi = 0; mi < 4; ++mi)
#pragma unroll
      for (int ni = 0; ni < 4; ++ni)
        acc[mi][ni] = (float4v){0.f, 0.f, 0.f, 0.f};

    for (int kc = 0; kc < 8; ++kc) {
#pragma unroll
      for (int i = 0; i < 4; ++i) {
        const int gid = tid + i * 256;
        const int row = gid >> 3, cg = gid & 7;
        const float* Ag = A + (size_t)(mbase + row) * 512 + kc * 64 + cg * 8;
        float4 f0 = *(const float4*)(Ag);
        float4 f1 = *(const float4*)(Ag + 4);
        union { short8v v; __hip_bfloat162 h2[4]; } pa;
        pa.h2[0] = __float22bfloat162_rn({f0.x, f0.y});
        pa.h2[1] = __float22bfloat162_rn({f0.z, f0.w});
        pa.h2[2] = __float22bfloat162_rn({f1.x, f1.y});
        pa.h2[3] = __float22bfloat162_rn({f1.z, f1.w});
        const int byte = (row * 128 + cg * 16) ^ ((row & 7) << 4);
        *(short8v*)&As[byte >> 1] = pa.v;
      }
      __syncthreads();

#pragma unroll
      for (int k0s = 0; k0s < 2; ++k0s) {
        short8v af[4], bf[4];
#pragma unroll
        for (int mi = 0; mi < 4; ++mi) {
          const int row = wr * 64 + mi * 16 + r;
          const int byte = (row * 128 + k0s * 64 + q * 16) ^ ((row & 7) << 4);
          af[mi] = *(short8v*)&As[byte >> 1];
        }
#pragma unroll
        for (int ni = 0; ni < 4; ++ni) {
          const int row = wc * 64 + ni * 16 + r;
          const int byte = (row * 1024 + kc * 128 + k0s * 64 + q * 16) ^ ((row & 7) << 4);
          bf[ni] = *(short8v*)&Bs[byte >> 1];
        }
#pragma unroll
        for (int mi = 0; mi < 4; ++mi)
#pragma unroll
          for (int ni = 0; ni < 4; ++ni)
            acc[mi][ni] = __builtin_amdgcn_mfma_f32_16x16x32_bf16(af[mi], bf[ni], acc[mi][ni], 0, 0, 0);
      }
      __syncthreads();
    }

    const int mg = mbase + wr * 64;
    const int ng = nbase + wc * 64;
#pragma unroll
    for (int ni = 0; ni < 4; ++ni) {
      const int col = ng + ni * 16 + r;
      const float bj = bias[col];
#pragma unroll
      for (int mi = 0; mi < 4; ++mi) {
        const int rowb = mg + mi * 16 + q * 4;
        float4v v = acc[mi][ni];
        C[(size_t)(rowb + 0) * V_ + col] = v[0] + bj;
        C[(size_t)(rowb + 1) * V_ + col] = v[1] + bj;
        C[(size_t)(rowb + 2) * V_ + col] = v[2] + bj;
        C[(size_t)(rowb + 3) * V_ + col] = v[3] + bj;
      }
    }
  }
}

extern "C" void kernel_launch(void* const* d_in, const int* in_sizes, int n_in,
                              void* d_out, int out_size, void* d_ws, size_t ws_size,
                              hipStream_t stream)
{
  const int*   tgt    = (const int*)  d_in[0];
  const float* hidden = (const float*)d_in[1];
  const float* enc    = (const float*)d_in[2];
  const float* embed  = (const float*)d_in[3];
  const float* W_ih0  = (const float*)d_in[4];
  const float* W_hh0  = (const float*)d_in[5];
  const float* b_ih0  = (const float*)d_in[6];
  const float* b_hh0  = (const float*)d_in[7];
  const float* W_ih1  = (const float*)d_in[8];
  const float* W_hh1  = (const float*)d_in[9];
  const float* b_ih1  = (const float*)d_in[10];
  const float* b_hh1  = (const float*)d_in[11];
  const float* W_out  = (const float*)d_in[12];
  const float* b_out  = (const float*)d_in[13];
  float* out = (float*)d_out;

  float* ws   = (float*)d_ws;
  float* xbuf = ws;                          // 2048*512  (attn_out)
  float* xg   = ws + 1048576;                // 2048*1536
  float* out0 = xg + 3145728;                // 2048*512
  float* y1   = out0 + 1048576;              // 2048*512 (contiguous after out0)

  const size_t logitsN = (size_t)(B_*T_) * V_;
  float* hn = out + logitsN;
  float* cn = hn + 16384;

  hipMemsetAsync(cn, 0, (size_t)16384 * sizeof(float), stream);

  k_fill<<<dim3(4096), dim3(512), 0, stream>>>((unsigned int*)out0, 2097152); // out0+y1
  k_xg_bf16<<<dim3(1536/128, 2048/128), dim3(256), 0, stream>>>(tgt, embed, W_ih0, b_ih0, xg);
  k_gru2<<<dim3(256), dim3(256), 0, stream>>>(xg, W_hh0, b_hh0, W_ih1, b_ih1,
                                              W_hh1, b_hh1, hidden, out0, y1, hn);
  k_attn<<<dim3(B_*T_), dim3(256), 0, stream>>>(y1, enc, xbuf);
  k_logits<<<dim3(V_/128), dim3(256), 0, stream>>>(xbuf, W_out, b_out, out);
}

// Round 13
// 1294.383 us; speedup vs baseline: 1.3740x; 1.0080x over previous
//
#include <hip/hip_runtime.h>
#include <hip/hip_bf16.h>
#include <math.h>

#define B_ 16
#define T_ 128
#define S_ 256
#define H_ 512
#define M_ 512
#define V_ 32000
#define SENT 0x7FC0DEADu
#define HPAD 524

typedef __attribute__((ext_vector_type(8))) short short8v;
typedef __attribute__((ext_vector_type(4))) float float4v;

// ---------------- sentinel fill ----------------
__global__ __launch_bounds__(512) void k_fill(unsigned int* __restrict__ p, int n)
{
  const int i = blockIdx.x * 512 + threadIdx.x;
  if (i < n) p[i] = SENT;
}

// ---------------- gather-fused bf16 MFMA GEMM for xg0 ----------------
__global__ __launch_bounds__(256) void k_xg_bf16(const int* __restrict__ tgt,
    const float* __restrict__ embed, const float* __restrict__ Bm,
    const float* __restrict__ bias, float* __restrict__ C)
{
  __shared__ unsigned short As[128 * 40];
  __shared__ unsigned short Bs[128 * 40];
  const int tid = threadIdx.x;
  const int nbase = blockIdx.x * 128;
  const int mbase = blockIdx.y * 128;
  const int wv = tid >> 6;
  const int l  = tid & 63;
  const int wr = wv >> 1, wc = wv & 1;
  const int r = l & 15, q = l >> 4;

  const int row0 = tid >> 2, row1 = (tid + 256) >> 2;
  const int v0 = tgt[mbase + row0];
  const int v1 = tgt[mbase + row1];

  float4v acc[4][4];
#pragma unroll
  for (int mi = 0; mi < 4; ++mi)
#pragma unroll
    for (int ni = 0; ni < 4; ++ni)
      acc[mi][ni] = (float4v){0.f, 0.f, 0.f, 0.f};

  for (int k0 = 0; k0 < 512; k0 += 32) {
    __syncthreads();
#pragma unroll
    for (int h = 0; h < 2; ++h) {
      const int c = tid + h * 256;
      const int row = h ? row1 : row0;
      const int av  = h ? v1 : v0;
      const int cb = c & 3;
      const float* Ag = embed + (size_t)av * 512 + k0 + cb * 8;
      float4 f0 = *(const float4*)(Ag);
      float4 f1 = *(const float4*)(Ag + 4);
      union { short8v v; __hip_bfloat162 h2[4]; } pa;
      pa.h2[0] = __float22bfloat162_rn({f0.x, f0.y});
      pa.h2[1] = __float22bfloat162_rn({f0.z, f0.w});
      pa.h2[2] = __float22bfloat162_rn({f1.x, f1.y});
      pa.h2[3] = __float22bfloat162_rn({f1.z, f1.w});
      *(short8v*)&As[row * 40 + cb * 8] = pa.v;
      const float* Bg = Bm + (size_t)(nbase + row) * 512 + k0 + cb * 8;
      float4 g0 = *(const float4*)(Bg);
      float4 g1 = *(const float4*)(Bg + 4);
      union { short8v v; __hip_bfloat162 h2[4]; } pb;
      pb.h2[0] = __float22bfloat162_rn({g0.x, g0.y});
      pb.h2[1] = __float22bfloat162_rn({g0.z, g0.w});
      pb.h2[2] = __float22bfloat162_rn({g1.x, g1.y});
      pb.h2[3] = __float22bfloat162_rn({g1.z, g1.w});
      *(short8v*)&Bs[row * 40 + cb * 8] = pb.v;
    }
    __syncthreads();

    short8v af[4], bf[4];
#pragma unroll
    for (int mi = 0; mi < 4; ++mi)
      af[mi] = *(short8v*)&As[(wr * 64 + mi * 16 + r) * 40 + q * 8];
#pragma unroll
    for (int ni = 0; ni < 4; ++ni)
      bf[ni] = *(short8v*)&Bs[(wc * 64 + ni * 16 + r) * 40 + q * 8];
#pragma unroll
    for (int mi = 0; mi < 4; ++mi)
#pragma unroll
      for (int ni = 0; ni < 4; ++ni)
        acc[mi][ni] = __builtin_amdgcn_mfma_f32_16x16x32_bf16(af[mi], bf[ni], acc[mi][ni], 0, 0, 0);
  }

  const int mg = mbase + wr * 64;
  const int ng = nbase + wc * 64;
#pragma unroll
  for (int ni = 0; ni < 4; ++ni) {
    const int col = ng + ni * 16 + r;
    const float bj = bias[col];
#pragma unroll
    for (int mi = 0; mi < 4; ++mi) {
      const int rowb = mg + mi * 16 + q * 4;
      float4v v = acc[mi][ni];
      C[(size_t)(rowb + 0) * 1536 + col] = v[0] + bj;
      C[(size_t)(rowb + 1) * 1536 + col] = v[1] + bj;
      C[(size_t)(rowb + 2) * 1536 + col] = v[2] + bj;
      C[(size_t)(rowb + 3) * 1536 + col] = v[3] + bj;
    }
  }
}

// bulk coherent load: 8x dwordx4, LLC-visible (sc0 sc1), single waitcnt.
struct F4x8 { float4 a, b, c, d, e, f, g, h; };
__device__ inline F4x8 bulk8_ld(const float* rowbase, int sc)
{
  F4x8 r;
  const float* p = rowbase + sc * 4;
  asm volatile(
    "global_load_dwordx4 %0, %[p], off sc0 sc1\n\t"
    "global_load_dwordx4 %1, %[p], off offset:256 sc0 sc1\n\t"
    "global_load_dwordx4 %2, %[p], off offset:512 sc0 sc1\n\t"
    "global_load_dwordx4 %3, %[p], off offset:768 sc0 sc1\n\t"
    "global_load_dwordx4 %4, %[p], off offset:1024 sc0 sc1\n\t"
    "global_load_dwordx4 %5, %[p], off offset:1280 sc0 sc1\n\t"
    "global_load_dwordx4 %6, %[p], off offset:1536 sc0 sc1\n\t"
    "global_load_dwordx4 %7, %[p], off offset:1792 sc0 sc1\n\t"
    "s_waitcnt vmcnt(0)"
    : "=&v"(r.a), "=&v"(r.b), "=&v"(r.c), "=&v"(r.d),
      "=&v"(r.e), "=&v"(r.f), "=&v"(r.g), "=&v"(r.h)
    : [p]"v"(p)
    : "memory");
  return r;
}

// dual bulk load: 16 loads in flight, ONE waitcnt (merges L1's two stages)
__device__ inline void bulk16_ld(const float* r0base, const float* r1base, int sc,
                                 F4x8& x, F4x8& y)
{
  const float* p0 = r0base + sc * 4;
  const float* p1 = r1base + sc * 4;
  asm volatile(
    "global_load_dwordx4 %0, %[p0], off sc0 sc1\n\t"
    "global_load_dwordx4 %1, %[p0], off offset:256 sc0 sc1\n\t"
    "global_load_dwordx4 %2, %[p0], off offset:512 sc0 sc1\n\t"
    "global_load_dwordx4 %3, %[p0], off offset:768 sc0 sc1\n\t"
    "global_load_dwordx4 %4, %[p0], off offset:1024 sc0 sc1\n\t"
    "global_load_dwordx4 %5, %[p0], off offset:1280 sc0 sc1\n\t"
    "global_load_dwordx4 %6, %[p0], off offset:1536 sc0 sc1\n\t"
    "global_load_dwordx4 %7, %[p0], off offset:1792 sc0 sc1\n\t"
    "global_load_dwordx4 %8, %[p1], off sc0 sc1\n\t"
    "global_load_dwordx4 %9, %[p1], off offset:256 sc0 sc1\n\t"
    "global_load_dwordx4 %10, %[p1], off offset:512 sc0 sc1\n\t"
    "global_load_dwordx4 %11, %[p1], off offset:768 sc0 sc1\n\t"
    "global_load_dwordx4 %12, %[p1], off offset:1024 sc0 sc1\n\t"
    "global_load_dwordx4 %13, %[p1], off offset:1280 sc0 sc1\n\t"
    "global_load_dwordx4 %14, %[p1], off offset:1536 sc0 sc1\n\t"
    "global_load_dwordx4 %15, %[p1], off offset:1792 sc0 sc1\n\t"
    "s_waitcnt vmcnt(0)"
    : "=&v"(x.a), "=&v"(x.b), "=&v"(x.c), "=&v"(x.d),
      "=&v"(x.e), "=&v"(x.f), "=&v"(x.g), "=&v"(x.h),
      "=&v"(y.a), "=&v"(y.b), "=&v"(y.c), "=&v"(y.d),
      "=&v"(y.e), "=&v"(y.f), "=&v"(y.g), "=&v"(y.h)
    : [p0]"v"(p0), [p1]"v"(p1)
    : "memory");
}

__device__ inline bool anysent(const F4x8& r)
{
  auto c1 = [](float4 v) {
    return (__float_as_uint(v.x) == SENT) | (__float_as_uint(v.y) == SENT) |
           (__float_as_uint(v.z) == SENT) | (__float_as_uint(v.w) == SENT);
  };
  return c1(r.a) | c1(r.b) | c1(r.c) | c1(r.d) |
         c1(r.e) | c1(r.f) | c1(r.g) | c1(r.h);
}

__device__ inline void f4x8_store(const F4x8& r, int sc, float* dstrow)
{
  *(float4*)&dstrow[(0*16 + sc) * 4] = r.a;
  *(float4*)&dstrow[(1*16 + sc) * 4] = r.b;
  *(float4*)&dstrow[(2*16 + sc) * 4] = r.c;
  *(float4*)&dstrow[(3*16 + sc) * 4] = r.d;
  *(float4*)&dstrow[(4*16 + sc) * 4] = r.e;
  *(float4*)&dstrow[(5*16 + sc) * 4] = r.f;
  *(float4*)&dstrow[(6*16 + sc) * 4] = r.g;
  *(float4*)&dstrow[(7*16 + sc) * 4] = r.h;
}

__device__ inline void stage_sent(const float* rowbase, int sc, float* dstrow)
{
  F4x8 r = bulk8_ld(rowbase, sc);
  while (anysent(r)) {
    __builtin_amdgcn_s_sleep(1);
    r = bulk8_ld(rowbase, sc);
  }
  f4x8_store(r, sc, dstrow);
}

__device__ inline void stage2_sent(const float* r0base, const float* r1base,
                                   int sc, float* d0, float* d1)
{
  F4x8 x, y;
  bulk16_ld(r0base, r1base, sc, x, y);
  while (anysent(x)) {
    __builtin_amdgcn_s_sleep(1);
    x = bulk8_ld(r0base, sc);
  }
  f4x8_store(x, sc, d0);
  while (anysent(y)) {
    __builtin_amdgcn_s_sleep(1);
    y = bulk8_ld(r1base, sc);
  }
  f4x8_store(y, sc, d1);
}

// ---------------- fused 2-layer GRU: sentinel dataflow, W in VGPRs ----------------
__global__ __launch_bounds__(256, 1) void k_gru2(
    const float* __restrict__ xg0,
    const float* __restrict__ Whh0, const float* __restrict__ bhh0,
    const float* __restrict__ Wih1, const float* __restrict__ bih1,
    const float* __restrict__ Whh1, const float* __restrict__ bhh1,
    const float* __restrict__ hidden,
    float* __restrict__ out0, float* __restrict__ y1, float* __restrict__ hn)
{
  __shared__ float Wl[24][520];
  __shared__ float hx[2][16 * HPAD];
  __shared__ float ps[24][16][17];
  const int bid = blockIdx.x;
  const int lt = threadIdx.x;

  // ---------------- heaters (quiet: one lane polls y1's last element) ----------------
  if (bid >= 192) {
    __shared__ int done;
    if (lt == 0) done = 0;
    __syncthreads();
    const float* flag = y1 + (size_t)(15 * T_ + 127) * 512 + 511;
    float a0 = 1.0f + lt, a1 = 2.0f + lt, a2 = 3.0f, a3 = 4.0f;
    const float mb = 1.0001f, cb = 0.9999f;
    for (;;) {
#pragma unroll 16
      for (int i = 0; i < 512; ++i) {
        a0 = __builtin_fmaf(a0, mb, cb); a1 = __builtin_fmaf(a1, mb, cb);
        a2 = __builtin_fmaf(a2, mb, cb); a3 = __builtin_fmaf(a3, mb, cb);
      }
      if (lt == 0 &&
          __float_as_uint(__hip_atomic_load(flag, __ATOMIC_RELAXED,
                                            __HIP_MEMORY_SCOPE_AGENT)) != SENT)
        done = 1;
      __syncthreads();
      if (done) break;
    }
    asm volatile("" :: "v"(a0), "v"(a1), "v"(a2), "v"(a3));
    return;
  }

  const bool isB = bid >= 64;
  const int wg = isB ? bid - 64 : bid;
  const int dbase = isB ? wg * 4 : wg * 8;

  for (int r = 0; r < 24; ++r) {
    const float* src;
    if (!isB) src = Whh0 + (size_t)((r >> 3) * 512 + dbase + (r & 7)) * 512;
    else if (r < 12) src = Whh1 + (size_t)((r >> 2) * 512 + dbase + (r & 3)) * 512;
    else { int rr = r - 12; src = Wih1 + (size_t)((rr >> 2) * 512 + dbase + (rr & 3)) * 512; }
    Wl[r][lt] = src[lt];
    Wl[r][lt + 256] = src[lt + 256];
  }

  const int kq = lt & 15;
  const int bq = (lt >> 4) & 3;
  const int rgrp = lt >> 6;
  const int sb = lt >> 4;
  const int sc = lt & 15;
  float* ybuf = isB ? y1 : out0;
  const float* h0g = hidden + (isB ? 8192 : 0);

  const int rb = isB ? (lt >> 2) : (lt >> 3);
  const int rdl = isB ? (lt & 3) : (lt & 7);
  const int rdg = dbase + rdl;
  const int nred = isB ? 64 : 128;
  float bhr = 0.f, bhz = 0.f, bhn = 0.f, bir = 0.f, biz = 0.f, bin_ = 0.f;
  if (lt < nred) {
    const float* bhh = isB ? bhh1 : bhh0;
    bhr = bhh[rdg]; bhz = bhh[512 + rdg]; bhn = bhh[1024 + rdg];
    if (isB) { bir = bih1[rdg]; biz = bih1[512 + rdg]; bin_ = bih1[1024 + rdg]; }
  }
  __syncthreads();

  // ---- copy this thread's 6 W-rows x 32 k into registers (static across t) ----
  float4 wreg[6][8];
#pragma unroll
  for (int jr = 0; jr < 6; ++jr)
#pragma unroll
    for (int i = 0; i < 8; ++i)
      wreg[jr][i] = *(const float4*)(&Wl[rgrp * 6 + jr][kq * 4 + i * 64]);

  for (int t = 0; t < T_; ++t) {
    // ---- xg prefetch (L0 reducers): issue early, consumed after B2 ----
    float pxr = 0.f, pxz = 0.f, pxn = 0.f;
    if (!isB && lt < 128) {
      const float* xrow = xg0 + (size_t)(rb * T_ + t) * 1536;
      pxr = xrow[rdg]; pxz = xrow[512 + rdg]; pxn = xrow[1024 + rdg];
    }

    // ---- S: stage h rows (sentinel-retry bulk loads) ----
    if (t == 0) {
#pragma unroll
      for (int j = 0; j < 8; ++j)
        *(float4*)&hx[0][sb * HPAD + (j * 16 + sc) * 4] =
            *(const float4*)(h0g + sb * 512 + (j * 16 + sc) * 4);
      if (isB)
        stage_sent(out0 + (size_t)(sb * T_) * 512, sc, &hx[1][sb * HPAD]);
    } else if (!isB) {
      stage_sent(ybuf + (size_t)(sb * T_ + t - 1) * 512, sc, &hx[0][sb * HPAD]);
    } else {
      stage2_sent(ybuf + (size_t)(sb * T_ + t - 1) * 512,
                  out0 + (size_t)(sb * T_ + t) * 512,
                  sc, &hx[0][sb * HPAD], &hx[1][sb * HPAD]);
    }
    __syncthreads();                                   // B1

    // ---- M: register-tiled matvec (W from VGPRs, h from LDS) ----
    const float* inb = (isB && rgrp >= 2) ? &hx[1][0] : &hx[0][0];
    float acc[6][4];
#pragma unroll
    for (int jr = 0; jr < 6; ++jr)
#pragma unroll
      for (int jb = 0; jb < 4; ++jb) acc[jr][jb] = 0.f;
#pragma unroll
    for (int i = 0; i < 8; ++i) {
      const int kb = kq * 4 + i * 64;
      float4 hv0 = *(const float4*)(inb + (bq * 4 + 0) * HPAD + kb);
      float4 hv1 = *(const float4*)(inb + (bq * 4 + 1) * HPAD + kb);
      float4 hv2 = *(const float4*)(inb + (bq * 4 + 2) * HPAD + kb);
      float4 hv3 = *(const float4*)(inb + (bq * 4 + 3) * HPAD + kb);
#pragma unroll
      for (int jr = 0; jr < 6; ++jr) {
        float4 wv = wreg[jr][i];
        acc[jr][0] += wv.x*hv0.x + wv.y*hv0.y + wv.z*hv0.z + wv.w*hv0.w;
        acc[jr][1] += wv.x*hv1.x + wv.y*hv1.y + wv.z*hv1.z + wv.w*hv1.w;
        acc[jr][2] += wv.x*hv2.x + wv.y*hv2.y + wv.z*hv2.z + wv.w*hv2.w;
        acc[jr][3] += wv.x*hv3.x + wv.y*hv3.y + wv.z*hv3.z + wv.w*hv3.w;
      }
    }
#pragma unroll
    for (int jr = 0; jr < 6; ++jr)
#pragma unroll
      for (int jb = 0; jb < 4; ++jb)
        ps[rgrp * 6 + jr][bq * 4 + jb][kq] = acc[jr][jb];
    __syncthreads();                                   // B2

    // ---- R: reduce + activations + store ----
    if (lt < nred) {
      float ghr, ghz, ghn, ixr, ixz, ixn;
      if (!isB) {
        float s0 = 0.f, s1 = 0.f, s2 = 0.f;
#pragma unroll
        for (int q = 0; q < 16; ++q) {
          s0 += ps[rdl][rb][q];
          s1 += ps[8 + rdl][rb][q];
          s2 += ps[16 + rdl][rb][q];
        }
        ghr = s0 + bhr; ghz = s1 + bhz; ghn = s2 + bhn;
        ixr = pxr; ixz = pxz; ixn = pxn;
      } else {
        float s0=0.f,s1=0.f,s2=0.f,s3=0.f,s4=0.f,s5=0.f;
#pragma unroll
        for (int q = 0; q < 16; ++q) {
          s0 += ps[rdl][rb][q];       s1 += ps[4 + rdl][rb][q];  s2 += ps[8 + rdl][rb][q];
          s3 += ps[12 + rdl][rb][q];  s4 += ps[16 + rdl][rb][q]; s5 += ps[20 + rdl][rb][q];
        }
        ghr = s0 + bhr; ghz = s1 + bhz; ghn = s2 + bhn;
        ixr = s3 + bir; ixz = s4 + biz; ixn = s5 + bin_;
      }
      float rr = 1.f / (1.f + expf(-(ixr + ghr)));
      float zz = 1.f / (1.f + expf(-(ixz + ghz)));
      float nn = tanhf(ixn + rr * ghn);
      float hp = hx[0][rb * HPAD + rdg];
      float hnew = (1.f - zz) * nn + zz * hp;
      __hip_atomic_store(&ybuf[(size_t)(rb * T_ + t) * 512 + rdg], hnew,
                         __ATOMIC_RELAXED, __HIP_MEMORY_SCOPE_AGENT);
      if (t == T_ - 1) hn[(isB ? 8192 : 0) + rb * 512 + rdg] = hnew;
    }
    __syncthreads();                                   // B3: protect hx before next stage
  }
}

// ---------------- attention: one WG per (b,t) row, bf16 output ----------------
__global__ __launch_bounds__(256) void k_attn(const float* __restrict__ y,
    const float* __restrict__ enc, __hip_bfloat162* __restrict__ abf)
{
  __shared__ float orow[512];
  __shared__ float wbuf[256];
  __shared__ float red[8];
  const int row = blockIdx.x;        // b*T+t
  const int b = row >> 7;
  const int lt = threadIdx.x;
  orow[lt]       = y[(size_t)row*512 + lt];
  orow[lt + 256] = y[(size_t)row*512 + lt + 256];
  __syncthreads();
  const float* er = enc + (size_t)(b*S_ + lt) * 512;
  float acc = 0.f;
  for (int k = 0; k < 512; k += 4) {
    float4 e = *(const float4*)(er + k);
    acc += orow[k]*e.x + orow[k+1]*e.y + orow[k+2]*e.z + orow[k+3]*e.w;
  }
  float m = acc;
#pragma unroll
  for (int off = 32; off > 0; off >>= 1) m = fmaxf(m, __shfl_down(m, off));
  if ((lt & 63) == 0) red[lt >> 6] = m;
  __syncthreads();
  float mx = fmaxf(fmaxf(red[0], red[1]), fmaxf(red[2], red[3]));
  float e = expf(acc - mx);
  wbuf[lt] = e;
  float s = e;
#pragma unroll
  for (int off = 32; off > 0; off >>= 1) s += __shfl_down(s, off);
  if ((lt & 63) == 0) red[4 + (lt >> 6)] = s;
  __syncthreads();
  const float inv = 1.f / (red[4] + red[5] + red[6] + red[7]);
  const int kk = lt * 2;
  float c0 = 0.f, c1 = 0.f;
  for (int s2 = 0; s2 < S_; ++s2) {
    float ws = wbuf[s2];
    float2 ev = *(const float2*)(enc + (size_t)(b*S_ + s2)*512 + kk);
    c0 += ws * ev.x; c1 += ws * ev.y;
  }
  abf[(size_t)row * 256 + lt] =
      __float22bfloat162_rn({orow[kk] + c0 * inv, orow[kk + 1] + c1 * inv});
}

// ---------------- persistent-B bf16 MFMA logits GEMM (bf16 A, early-issue) ----------------
__global__ __launch_bounds__(256) void k_logits(const unsigned short* __restrict__ Abf,
    const float* __restrict__ Bm, const float* __restrict__ bias,
    float* __restrict__ C)
{
  __shared__ unsigned short Bs[128 * 512];   // swizzled: byte ^= (row&7)<<4
  __shared__ unsigned short As[128 * 64];
  const int tid = threadIdx.x;
  const int nbase = blockIdx.x * 128;
  const int wv = tid >> 6;
  const int l  = tid & 63;
  const int wr = wv >> 1, wc = wv & 1;
  const int r = l & 15, q = l >> 4;

  for (int i = 0; i < 32; ++i) {
    const int gid = tid + i * 256;
    const int row = gid >> 6, cg = gid & 63;
    const float* Bg = Bm + (size_t)(nbase + row) * 512 + cg * 8;
    float4 g0 = *(const float4*)(Bg);
    float4 g1 = *(const float4*)(Bg + 4);
    union { short8v v; __hip_bfloat162 h2[4]; } pb;
    pb.h2[0] = __float22bfloat162_rn({g0.x, g0.y});
    pb.h2[1] = __float22bfloat162_rn({g0.z, g0.w});
    pb.h2[2] = __float22bfloat162_rn({g1.x, g1.y});
    pb.h2[3] = __float22bfloat162_rn({g1.z, g1.w});
    const int byte = (row * 1024 + cg * 16) ^ ((row & 7) << 4);
    *(short8v*)&Bs[byte >> 1] = pb.v;
  }

  int arow[4], acg[4], abyte[4];
#pragma unroll
  for (int i = 0; i < 4; ++i) {
    const int gid = tid + i * 256;
    arow[i] = gid >> 3; acg[i] = gid & 7;
    abyte[i] = (arow[i] * 128 + acg[i] * 16) ^ ((arow[i] & 7) << 4);
  }
  __syncthreads();

  for (int m = 0; m < 16; ++m) {
    const int mbase = m * 128;
    float4v acc[4][4];
#pragma unroll
    for (int mi = 0; mi < 4; ++mi)
#pragma unroll
      for (int ni = 0; ni < 4; ++ni)
        acc[mi][ni] = (float4v){0.f, 0.f, 0.f, 0.f};

    // prologue: stage A chunk kc=0
    {
      short8v a0[4];
#pragma unroll
      for (int i = 0; i < 4; ++i)
        a0[i] = *(const short8v*)(Abf + (size_t)(mbase + arow[i]) * 512 + acg[i] * 8);
      __syncthreads();
#pragma unroll
      for (int i = 0; i < 4; ++i)
        *(short8v*)&As[abyte[i] >> 1] = a0[i];
      __syncthreads();
    }

    for (int kc = 0; kc < 8; ++kc) {
      // early-issue next A chunk (latency hidden under MFMA phase)
      short8v anext[4];
      if (kc < 7) {
#pragma unroll
        for (int i = 0; i < 4; ++i)
          anext[i] = *(const short8v*)(Abf + (size_t)(mbase + arow[i]) * 512 +
                                       (kc + 1) * 64 + acg[i] * 8);
      }

#pragma unroll
      for (int k0s = 0; k0s < 2; ++k0s) {
        short8v af[4], bf[4];
#pragma unroll
        for (int mi = 0; mi < 4; ++mi) {
          const int row = wr * 64 + mi * 16 + r;
          const int byte = (row * 128 + k0s * 64 + q * 16) ^ ((row & 7) << 4);
          af[mi] = *(short8v*)&As[byte >> 1];
        }
#pragma unroll
        for (int ni = 0; ni < 4; ++ni) {
          const int row = wc * 64 + ni * 16 + r;
          const int byte = (row * 1024 + kc * 128 + k0s * 64 + q * 16) ^ ((row & 7) << 4);
          bf[ni] = *(short8v*)&Bs[byte >> 1];
        }
#pragma unroll
        for (int mi = 0; mi < 4; ++mi)
#pragma unroll
          for (int ni = 0; ni < 4; ++ni)
            acc[mi][ni] = __builtin_amdgcn_mfma_f32_16x16x32_bf16(af[mi], bf[ni], acc[mi][ni], 0, 0, 0);
      }
      __syncthreads();           // all waves done reading As
      if (kc < 7) {
#pragma unroll
        for (int i = 0; i < 4; ++i)
          *(short8v*)&As[abyte[i] >> 1] = anext[i];
      }
      __syncthreads();           // As refilled for next kc
    }

    const int mg = mbase + wr * 64;
    const int ng = nbase + wc * 64;
#pragma unroll
    for (int ni = 0; ni < 4; ++ni) {
      const int col = ng + ni * 16 + r;
      const float bj = bias[col];
#pragma unroll
      for (int mi = 0; mi < 4; ++mi) {
        const int rowb = mg + mi * 16 + q * 4;
        float4v v = acc[mi][ni];
        C[(size_t)(rowb + 0) * V_ + col] = v[0] + bj;
        C[(size_t)(rowb + 1) * V_ + col] = v[1] + bj;
        C[(size_t)(rowb + 2) * V_ + col] = v[2] + bj;
        C[(size_t)(rowb + 3) * V_ + col] = v[3] + bj;
      }
    }
  }
}

extern "C" void kernel_launch(void* const* d_in, const int* in_sizes, int n_in,
                              void* d_out, int out_size, void* d_ws, size_t ws_size,
                              hipStream_t stream)
{
  const int*   tgt    = (const int*)  d_in[0];
  const float* hidden = (const float*)d_in[1];
  const float* enc    = (const float*)d_in[2];
  const float* embed  = (const float*)d_in[3];
  const float* W_ih0  = (const float*)d_in[4];
  const float* W_hh0  = (const float*)d_in[5];
  const float* b_ih0  = (const float*)d_in[6];
  const float* b_hh0  = (const float*)d_in[7];
  const float* W_ih1  = (const float*)d_in[8];
  const float* W_hh1  = (const float*)d_in[9];
  const float* b_ih1  = (const float*)d_in[10];
  const float* b_hh1  = (const float*)d_in[11];
  const float* W_out  = (const float*)d_in[12];
  const float* b_out  = (const float*)d_in[13];
  float* out = (float*)d_out;

  float* ws   = (float*)d_ws;
  __hip_bfloat162* abf = (__hip_bfloat162*)ws;   // 2048*256 bf16x2 (2 MB, attn out)
  float* xg   = ws + 1048576;                    // 2048*1536
  float* out0 = xg + 3145728;                    // 2048*512
  float* y1   = out0 + 1048576;                  // 2048*512 (contiguous after out0)

  const size_t logitsN = (size_t)(B_*T_) * V_;
  float* hn = out + logitsN;
  float* cn = hn + 16384;

  hipMemsetAsync(cn, 0, (size_t)16384 * sizeof(float), stream);

  k_fill<<<dim3(4096), dim3(512), 0, stream>>>((unsigned int*)out0, 2097152); // out0+y1
  k_xg_bf16<<<dim3(1536/128, 2048/128), dim3(256), 0, stream>>>(tgt, embed, W_ih0, b_ih0, xg);
  k_gru2<<<dim3(256), dim3(256), 0, stream>>>(xg, W_hh0, b_hh0, W_ih1, b_ih1,
                                              W_hh1, b_hh1, hidden, out0, y1, hn);
  k_attn<<<dim3(B_*T_), dim3(256), 0, stream>>>(y1, enc, abf);
  k_logits<<<dim3(V_/128), dim3(256), 0, stream>>>((const unsigned short*)abf,
                                                   W_out, b_out, out);
}